// Round 2
// baseline (1865.641 us; speedup 1.0000x reference)
//
#include <hip/hip_runtime.h>
#include <hip/hip_bf16.h>
#include <stdint.h>

// ---------------------------------------------------------------------------
// AttentionBlock: q/k/v ctx-proj (GEMM + masked-BN + relu + L2norm), attention
// (QK^T -> masked softmax -> PV), f ctx-proj (GEMM + masked-BN + relu), masked.
// All matmuls bf16 MFMA. fp32->bf16 conversion fused into GEMM staging (no
// input copies); workspace aliased by lifetime -> peak 335.6 MB.
// ---------------------------------------------------------------------------

typedef __attribute__((ext_vector_type(8))) short short8;
typedef __attribute__((ext_vector_type(4))) float floatx4;

__device__ __forceinline__ float bf2f(short h) {
    union { unsigned u; float f; } c;
    c.u = ((unsigned)(unsigned short)h) << 16;
    return c.f;
}
__device__ __forceinline__ short f2bf(float f) {
    union { float f; unsigned u; } c;
    c.f = f;
    unsigned u = c.u + 0x7fffu + ((c.u >> 16) & 1u);  // RNE
    return (short)(u >> 16);
}

// 8 contiguous fp32 (32B-aligned, in-bounds) -> bf16x8
__device__ __forceinline__ short8 cvt8load(const float* p) {
    float4 f0 = *(const float4*)(p);
    float4 f1 = *(const float4*)(p + 4);
    short8 r;
    r[0] = f2bf(f0.x); r[1] = f2bf(f0.y); r[2] = f2bf(f0.z); r[3] = f2bf(f0.w);
    r[4] = f2bf(f1.x); r[5] = f2bf(f1.y); r[6] = f2bf(f1.z); r[7] = f2bf(f1.w);
    return r;
}
// guarded scalar path (odd K stride / K-pad zero-fill)
__device__ __forceinline__ short8 cvt8guard(const float* row, int c0, int Kin) {
    short8 r;
#pragma unroll
    for (int j = 0; j < 8; j++) {
        int c = c0 + j;
        r[j] = (c < Kin) ? f2bf(row[c]) : (short)0;
    }
    return r;
}

// ---------------- BT GEMM: Y[m,n] = sum_k X[m,k] W[n,k] + bias[n] ----------
// 128x128 tile, BK=32, mfma 16x16x32 bf16. X fp32 (fused cvt) or bf16;
// W always fp32. Fused masked BN-stats via quad-shuffle + atomicAdd.
template<bool XBF16, bool KAL>
__global__ __launch_bounds__(256, 2)
void gemm_bt(const void* __restrict__ Xp, const float* __restrict__ W,
             const float* __restrict__ bias, short* __restrict__ Y,
             int N, int Kin, int Kp, float* __restrict__ stats,
             const int* __restrict__ lens, int Lshift)
{
    __shared__ short At[128 * 32];
    __shared__ short Bt[128 * 32];
    const int m0 = blockIdx.x * 128;
    const int n0 = blockIdx.y * 128;
    const int tid = threadIdx.x;
    const int w = tid >> 6, l = tid & 63;
    const int quad = l >> 4, l15 = l & 15;
    const int mo = (w & 1) * 64, no = (w >> 1) * 64;

    floatx4 acc[4][4];
#pragma unroll
    for (int i = 0; i < 4; i++)
#pragma unroll
        for (int j = 0; j < 4; j++) acc[i][j] = (floatx4){0.f, 0.f, 0.f, 0.f};

    const int srow = tid >> 2;        // 0..63
    const int sc8 = (tid & 3) * 8;    // 0,8,16,24

    for (int k0 = 0; k0 < Kp; k0 += 32) {
        __syncthreads();
        const int c0 = k0 + sc8;
        short8 a0, a1, b0, b1;
        if (XBF16) {
            const short* X = (const short*)Xp;
            a0 = *(const short8*)(X + (long)(m0 + srow) * Kp + c0);
            a1 = *(const short8*)(X + (long)(m0 + 64 + srow) * Kp + c0);
        } else {
            const float* X = (const float*)Xp;
            if (KAL) {
                a0 = cvt8load(X + (long)(m0 + srow) * Kin + c0);
                a1 = cvt8load(X + (long)(m0 + 64 + srow) * Kin + c0);
            } else {
                a0 = cvt8guard(X + (long)(m0 + srow) * Kin, c0, Kin);
                a1 = cvt8guard(X + (long)(m0 + 64 + srow) * Kin, c0, Kin);
            }
        }
        if (KAL) {
            b0 = cvt8load(W + (long)(n0 + srow) * Kin + c0);
            b1 = cvt8load(W + (long)(n0 + 64 + srow) * Kin + c0);
        } else {
            b0 = cvt8guard(W + (long)(n0 + srow) * Kin, c0, Kin);
            b1 = cvt8guard(W + (long)(n0 + 64 + srow) * Kin, c0, Kin);
        }
        *(short8*)(At + srow * 32 + sc8) = a0;
        *(short8*)(At + (64 + srow) * 32 + sc8) = a1;
        *(short8*)(Bt + srow * 32 + sc8) = b0;
        *(short8*)(Bt + (64 + srow) * 32 + sc8) = b1;
        __syncthreads();
        short8 af[4], bfr[4];
#pragma unroll
        for (int i = 0; i < 4; i++) {
            af[i]  = *(const short8*)(At + (mo + i * 16 + l15) * 32 + quad * 8);
            bfr[i] = *(const short8*)(Bt + (no + i * 16 + l15) * 32 + quad * 8);
        }
#pragma unroll
        for (int i = 0; i < 4; i++)
#pragma unroll
            for (int j = 0; j < 4; j++)
                acc[i][j] = __builtin_amdgcn_mfma_f32_16x16x32_bf16(af[i], bfr[j], acc[i][j], 0, 0, 0);
    }

    // epilogue: bias + store bf16 + masked stats
    const int Lmask = (1 << Lshift) - 1;
    float msk[4][4];
#pragma unroll
    for (int i = 0; i < 4; i++)
#pragma unroll
        for (int r = 0; r < 4; r++) {
            int rg = m0 + mo + i * 16 + quad * 4 + r;
            msk[i][r] = ((rg & Lmask) < lens[rg >> Lshift]) ? 1.f : 0.f;
        }
#pragma unroll
    for (int j = 0; j < 4; j++) {
        int colj = n0 + no + j * 16 + l15;
        float bv = bias[colj];
        float ps = 0.f, pss = 0.f;
#pragma unroll
        for (int i = 0; i < 4; i++)
#pragma unroll
            for (int r = 0; r < 4; r++) {
                int rg = m0 + mo + i * 16 + quad * 4 + r;
                float v = acc[i][j][r] + bv;
                Y[(long)rg * N + colj] = f2bf(v);
                ps += v * msk[i][r];
                pss += v * v * msk[i][r];
            }
        ps  += __shfl_xor(ps, 16, 64);  ps  += __shfl_xor(ps, 32, 64);
        pss += __shfl_xor(pss, 16, 64); pss += __shfl_xor(pss, 32, 64);
        if (l < 16) {
            atomicAdd(&stats[colj], ps);
            atomicAdd(&stats[N + colj], pss);
        }
    }
}

// ---------------- finalize: stats -> {scale, shift} per channel ------------
__global__ void finalize_stats(float* __restrict__ stats, const float* __restrict__ g,
                               const float* __restrict__ beta,
                               const int* __restrict__ lens, int C)
{
    __shared__ int lred[256];
    int t = threadIdx.x;
    if (t < 256) lred[t] = lens[t];
    __syncthreads();
    for (int s2 = 128; s2 > 0; s2 >>= 1) {
        if (t < s2) lred[t] += lred[t + s2];
        __syncthreads();
    }
    float cnt = (float)lred[0];
    if (t < C) {
        float mean = stats[t] / cnt;
        float var = fmaxf(stats[C + t] / cnt - mean * mean, 0.f);
        float a = rsqrtf(var + 1e-5f) * g[t];
        stats[t] = a;
        stats[C + t] = beta[t] - mean * a;
    }
}

// ---------------- BN + relu + row L2-normalize, C=512, in place ------------
__global__ __launch_bounds__(256)
void apply_norm512(short* __restrict__ Y, const float* __restrict__ stats)
{
    int w = threadIdx.x >> 6, l = threadIdx.x & 63;
    long row = (long)blockIdx.x * 4 + w;
    short8 yv = *(const short8*)(Y + row * 512 + l * 8);
    float v[8];
    float ss = 0.f;
#pragma unroll
    for (int i = 0; i < 8; i++) {
        int c = l * 8 + i;
        float t = fmaxf(bf2f(yv[i]) * stats[c] + stats[512 + c], 0.f);
        v[i] = t;
        ss += t * t;
    }
#pragma unroll
    for (int off = 1; off < 64; off <<= 1) ss += __shfl_xor(ss, off, 64);
    float scl = 1.f / fmaxf(sqrtf(ss), 1e-12f);
    short8 o;
#pragma unroll
    for (int i = 0; i < 8; i++) o[i] = f2bf(v[i] * scl);
    *(short8*)(Y + row * 512 + l * 8) = o;
}

// ---------------- v: BN + relu + L2norm, write transposed vT[s][d][b] ------
__global__ __launch_bounds__(256)
void apply_v_transpose(const short* __restrict__ Yv, short* __restrict__ vT,
                       const float* __restrict__ stats)
{
    __shared__ float post[16][513];
    __shared__ float partial[16][16];
    __shared__ float rss[16];
    int s = blockIdx.x >> 5;
    int b0 = (blockIdx.x & 31) * 16;
    int tid = threadIdx.x;
    int r = tid >> 4;           // 0..15 row within tile
    int cg = tid & 15;          // col group
    const short* src = Yv + ((long)(s * 512 + b0 + r)) * 512;
    float ss = 0.f;
#pragma unroll
    for (int i = 0; i < 4; i++) {
        int c0 = i * 128 + cg * 8;
        short8 yv = *(const short8*)(src + c0);
#pragma unroll
        for (int j = 0; j < 8; j++) {
            int c = c0 + j;
            float t = fmaxf(bf2f(yv[j]) * stats[c] + stats[512 + c], 0.f);
            post[r][c] = t;
            ss += t * t;
        }
    }
    partial[r][cg] = ss;
    __syncthreads();
    if (tid < 16) {
        float tot = 0.f;
#pragma unroll
        for (int j = 0; j < 16; j++) tot += partial[tid][j];
        rss[tid] = 1.f / fmaxf(sqrtf(tot), 1e-12f);
    }
    __syncthreads();
    short* dst = vT + (long)s * 512 * 512 + b0;
    for (int e = tid; e < 512 * 16; e += 256) {
        int d = e >> 4, b = e & 15;
        dst[(long)d * 512 + b] = f2bf(post[b][d] * rss[b]);
    }
}

// ---------------- attention: per (s, 64 a-rows) block ----------------------
__global__ __launch_bounds__(256)
void attention(const short* __restrict__ q, const short* __restrict__ k,
               const short* __restrict__ vT, const int* __restrict__ b_lens,
               short* __restrict__ wv)
{
    __shared__ short tile[32 * 520];     // k / vT staging (32 rows x 512, pad 8)
    __shared__ short Pscr[4][16 * 40];   // per-wave P relayout scratch
    const int s = blockIdx.y, a0 = blockIdx.x * 64;
    const int tid = threadIdx.x;
    const int w = tid >> 6, l = tid & 63;
    const int quad = l >> 4, l15 = l & 15;
    const int blen = b_lens[s];
    const int sr = tid >> 3;             // staging row 0..31
    const int scg = (tid & 7) * 8;       // staging col base

    short8 qf[16];
    const short* qbase = q + ((long)(s * 128 + a0 + w * 16 + l15)) * 512 + quad * 8;
#pragma unroll
    for (int kk = 0; kk < 16; kk++) qf[kk] = *(const short8*)(qbase + kk * 32);

    floatx4 sc[32];
#pragma unroll
    for (int i = 0; i < 32; i++) sc[i] = (floatx4){0.f, 0.f, 0.f, 0.f};

    const short* kbase = k + (long)s * 512 * 512;
    for (int bt2 = 0; bt2 < 16; ++bt2) {
        __syncthreads();
        const short* krow = kbase + (long)(bt2 * 32 + sr) * 512;
#pragma unroll
        for (int i = 0; i < 2; i++) {
            short8 t0 = *(const short8*)(krow + i * 256 + scg);
            short8 t1 = *(const short8*)(krow + i * 256 + 64 + scg);
            short8 t2 = *(const short8*)(krow + i * 256 + 128 + scg);
            short8 t3 = *(const short8*)(krow + i * 256 + 192 + scg);
            *(short8*)(&tile[sr * 520 + i * 256 + scg]) = t0;
            *(short8*)(&tile[sr * 520 + i * 256 + 64 + scg]) = t1;
            *(short8*)(&tile[sr * 520 + i * 256 + 128 + scg]) = t2;
            *(short8*)(&tile[sr * 520 + i * 256 + 192 + scg]) = t3;
        }
        __syncthreads();
#pragma unroll
        for (int kk = 0; kk < 16; kk++) {
            short8 f0 = *(const short8*)(&tile[l15 * 520 + kk * 32 + quad * 8]);
            short8 f1 = *(const short8*)(&tile[(16 + l15) * 520 + kk * 32 + quad * 8]);
            sc[bt2 * 2]     = __builtin_amdgcn_mfma_f32_16x16x32_bf16(qf[kk], f0, sc[bt2 * 2], 0, 0, 0);
            sc[bt2 * 2 + 1] = __builtin_amdgcn_mfma_f32_16x16x32_bf16(qf[kk], f1, sc[bt2 * 2 + 1], 0, 0, 0);
        }
    }

    // masked softmax along b. C-layout: col = bt*16+l15, row = quad*4+r
    const float scaler = 6.25f;  // 1/(0.01*sqrt(256))
    float mrow[4] = {-__builtin_inff(), -__builtin_inff(), -__builtin_inff(), -__builtin_inff()};
#pragma unroll
    for (int bt = 0; bt < 32; ++bt) {
        bool valid = (bt * 16 + l15) < blen;
#pragma unroll
        for (int r = 0; r < 4; r++) {
            float v = valid ? sc[bt][r] * scaler : -__builtin_inff();
            sc[bt][r] = v;
            mrow[r] = fmaxf(mrow[r], v);
        }
    }
#pragma unroll
    for (int r = 0; r < 4; r++) {
#pragma unroll
        for (int off = 1; off < 16; off <<= 1)
            mrow[r] = fmaxf(mrow[r], __shfl_xor(mrow[r], off, 64));
    }
    float ssum[4] = {0.f, 0.f, 0.f, 0.f};
#pragma unroll
    for (int bt = 0; bt < 32; ++bt)
#pragma unroll
        for (int r = 0; r < 4; r++) {
            float p = __expf(sc[bt][r] - mrow[r]);
            sc[bt][r] = p;
            ssum[r] += p;
        }
#pragma unroll
    for (int r = 0; r < 4; r++) {
#pragma unroll
        for (int off = 1; off < 16; off <<= 1) ssum[r] += __shfl_xor(ssum[r], off, 64);
        ssum[r] = 1.f / ssum[r];
    }

    // P: C-layout regs -> A-layout frags via per-wave LDS scratch
    short8 pf[16];
    short* Pw = Pscr[w];
#pragma unroll
    for (int kk = 0; kk < 16; kk++) {
#pragma unroll
        for (int half = 0; half < 2; half++)
#pragma unroll
            for (int r = 0; r < 4; r++)
                Pw[(quad * 4 + r) * 40 + half * 16 + l15] = f2bf(sc[kk * 2 + half][r] * ssum[r]);
        pf[kk] = *(const short8*)(&Pw[l15 * 40 + quad * 8]);
    }

    // phase 2: wv[a][d] = sum_b P[a][b] vT[d][b]
    const short* vbase = vT + (long)s * 512 * 512;
    short* wvbase = wv + ((long)(s * 128 + a0 + w * 16 + quad * 4)) * 512;
    for (int dt = 0; dt < 16; ++dt) {
        __syncthreads();
        const short* vrow = vbase + (long)(dt * 32 + sr) * 512;
#pragma unroll
        for (int i = 0; i < 2; i++) {
            short8 t0 = *(const short8*)(vrow + i * 256 + scg);
            short8 t1 = *(const short8*)(vrow + i * 256 + 64 + scg);
            short8 t2 = *(const short8*)(vrow + i * 256 + 128 + scg);
            short8 t3 = *(const short8*)(vrow + i * 256 + 192 + scg);
            *(short8*)(&tile[sr * 520 + i * 256 + scg]) = t0;
            *(short8*)(&tile[sr * 520 + i * 256 + 64 + scg]) = t1;
            *(short8*)(&tile[sr * 520 + i * 256 + 128 + scg]) = t2;
            *(short8*)(&tile[sr * 520 + i * 256 + 192 + scg]) = t3;
        }
        __syncthreads();
        floatx4 o0 = (floatx4){0.f, 0.f, 0.f, 0.f};
        floatx4 o1 = (floatx4){0.f, 0.f, 0.f, 0.f};
#pragma unroll
        for (int kk = 0; kk < 16; kk++) {
            short8 f0 = *(const short8*)(&tile[l15 * 520 + kk * 32 + quad * 8]);
            short8 f1 = *(const short8*)(&tile[(16 + l15) * 520 + kk * 32 + quad * 8]);
            o0 = __builtin_amdgcn_mfma_f32_16x16x32_bf16(pf[kk], f0, o0, 0, 0, 0);
            o1 = __builtin_amdgcn_mfma_f32_16x16x32_bf16(pf[kk], f1, o1, 0, 0, 0);
        }
#pragma unroll
        for (int r = 0; r < 4; r++) {
            wvbase[(long)r * 512 + dt * 32 + l15]      = f2bf(o0[r]);
            wvbase[(long)r * 512 + dt * 32 + 16 + l15] = f2bf(o1[r]);
        }
    }
}

// ---------------- f: BN + relu + mask_a -> d_out fp32 ----------------------
__global__ __launch_bounds__(256)
void apply_f(const short* __restrict__ Yf, const float* __restrict__ stats,
             const int* __restrict__ a_lens, float* __restrict__ out)
{
    const long total = (long)32768 * 256;
    for (long e = (long)blockIdx.x * 256 + threadIdx.x; e < total; e += (long)gridDim.x * 256) {
        int c = (int)(e & 255);
        long row = e >> 8;
        int sI = (int)(row >> 7), pos = (int)(row & 127);
        float v = fmaxf(bf2f(Yf[e]) * stats[c] + stats[256 + c], 0.f);
        out[e] = (pos < a_lens[sI]) ? v : 0.f;
    }
}

// ---------------------------------------------------------------------------
extern "C" void kernel_launch(void* const* d_in, const int* in_sizes, int n_in,
                              void* d_out, int out_size, void* d_ws, size_t ws_size,
                              hipStream_t stream)
{
    (void)in_sizes; (void)n_in; (void)out_size; (void)ws_size;
    const float* A     = (const float*)d_in[0];
    const float* B     = (const float*)d_in[1];
    const int* a_lens  = (const int*)d_in[2];
    const int* b_lens  = (const int*)d_in[3];
    const float* Wq    = (const float*)d_in[4];
    const float* bq    = (const float*)d_in[5];
    const float* gq    = (const float*)d_in[6];
    const float* betaq = (const float*)d_in[7];
    const float* Wk    = (const float*)d_in[8];
    const float* bk    = (const float*)d_in[9];
    const float* gk    = (const float*)d_in[10];
    const float* betak = (const float*)d_in[11];
    const float* Wv    = (const float*)d_in[12];
    const float* bv    = (const float*)d_in[13];
    const float* gv    = (const float*)d_in[14];
    const float* betav = (const float*)d_in[15];
    const float* Wf    = (const float*)d_in[16];
    const float* bfp   = (const float*)d_in[17];
    const float* gf    = (const float*)d_in[18];
    const float* betaf = (const float*)d_in[19];
    float* out = (float*)d_out;

    // workspace layout, aliased by lifetime (peak ~335.6 MB):
    //  [0]      qb   33.6MB   (q bf16)            ... later Yf (16.8MB)
    //  [33.6M]  Yv/kb 134.2MB (pre-BN v, then k)
    //  [167.8M] vT   134.2MB  (v normalized, transposed)
    //  [302.0M] wv   33.6MB   (attention out)
    //  [335.6M] stats 16KB
    char* base = (char*)d_ws;
    short* qb  = (short*)(base);
    short* Yv  = (short*)(base + 33554432);
    short* kb  = Yv;                                   // reuses Yv after transpose
    short* vT  = (short*)(base + 33554432 + 134217728);
    short* wvb = (short*)(base + 33554432 + 2L * 134217728);
    float* stQ = (float*)(base + 2L * 33554432 + 2L * 134217728);
    float* stK = stQ + 1024;
    float* stV = stQ + 2048;
    float* stF = stQ + 3072;
    short* Yf  = qb;                                   // reuses qb after attention

    hipMemsetAsync(stQ, 0, 4 * 4096, stream);

    // q projection: X=A fp32 (K=256 aligned), W=Wq fp32
    gemm_bt<false, true><<<dim3(256, 4), 256, 0, stream>>>(
        A, Wq, bq, qb, 512, 256, 256, stQ, a_lens, 7);

    // v projection: X=B fp32 (K=265, guarded/padded to 288), W=Wv fp32
    gemm_bt<false, false><<<dim3(1024, 4), 256, 0, stream>>>(
        B, Wv, bv, Yv, 512, 265, 288, stV, b_lens, 9);
    finalize_stats<<<1, 512, 0, stream>>>(stV, gv, betav, b_lens, 512);
    apply_v_transpose<<<8192, 256, 0, stream>>>(Yv, vT, stV);

    // k projection (kb overwrites Yv region — Yv dead after transpose)
    gemm_bt<false, false><<<dim3(1024, 4), 256, 0, stream>>>(
        B, Wk, bk, kb, 512, 265, 288, stK, b_lens, 9);
    finalize_stats<<<1, 512, 0, stream>>>(stK, gk, betak, b_lens, 512);
    apply_norm512<<<32768, 256, 0, stream>>>(kb, stK);

    finalize_stats<<<1, 512, 0, stream>>>(stQ, gq, betaq, a_lens, 512);
    apply_norm512<<<8192, 256, 0, stream>>>(qb, stQ);

    // attention
    attention<<<dim3(2, 256), 256, 0, stream>>>(qb, kb, vT, b_lens, wvb);

    // final projection: X=wvb bf16 (K=512), W=Wf fp32 (aligned); Yf aliases qb
    gemm_bt<true, true><<<dim3(256, 2), 256, 0, stream>>>(
        wvb, Wf, bfp, Yf, 256, 512, 512, stF, a_lens, 7);
    finalize_stats<<<1, 512, 0, stream>>>(stF, gf, betaf, a_lens, 256);
    apply_f<<<8192, 256, 0, stream>>>(Yf, stF, a_lens, out);
}

// Round 3
// 1049.418 us; speedup vs baseline: 1.7778x; 1.7778x over previous
//
#include <hip/hip_runtime.h>
#include <hip/hip_bf16.h>
#include <stdint.h>

// ---------------------------------------------------------------------------
// AttentionBlock: q/k/v ctx-proj (GEMM + masked-BN + relu + L2norm), attention
// (QK^T -> masked softmax -> PV), f ctx-proj (GEMM + masked-BN + relu), masked.
// Fast path (ws >= ~396MB): pre-convert operands to bf16 (K padded 265->288),
// GEMM stages via global_load_lds width=16 (m97 pattern). Fallback: R1 path
// (fused fp32->bf16 guarded staging, known correct, slower).
// ---------------------------------------------------------------------------

typedef __attribute__((ext_vector_type(8))) short short8;
typedef __attribute__((ext_vector_type(4))) float floatx4;

__device__ __forceinline__ float bf2f(short h) {
    union { unsigned u; float f; } c;
    c.u = ((unsigned)(unsigned short)h) << 16;
    return c.f;
}
__device__ __forceinline__ short f2bf(float f) {
    union { float f; unsigned u; } c;
    c.f = f;
    unsigned u = c.u + 0x7fffu + ((c.u >> 16) & 1u);  // RNE
    return (short)(u >> 16);
}

// async 16B global -> LDS (per-lane dest = wave base + lane*16, which our
// tid-contiguous staging layout satisfies)
__device__ __forceinline__ void async_cp16(const short* g, short* l) {
    __builtin_amdgcn_global_load_lds(
        (const __attribute__((address_space(1))) unsigned int*)g,
        (__attribute__((address_space(3))) unsigned int*)l, 16, 0, 0);
}

__device__ __forceinline__ short8 cvt8load(const float* p) {
    float4 f0 = *(const float4*)(p);
    float4 f1 = *(const float4*)(p + 4);
    short8 r;
    r[0] = f2bf(f0.x); r[1] = f2bf(f0.y); r[2] = f2bf(f0.z); r[3] = f2bf(f0.w);
    r[4] = f2bf(f1.x); r[5] = f2bf(f1.y); r[6] = f2bf(f1.z); r[7] = f2bf(f1.w);
    return r;
}
__device__ __forceinline__ short8 cvt8guard(const float* row, int c0, int Kin) {
    short8 r;
#pragma unroll
    for (int j = 0; j < 8; j++) {
        int c = c0 + j;
        r[j] = (c < Kin) ? f2bf(row[c]) : (short)0;
    }
    return r;
}

// ---------------- convert fp32 -> bf16 with K padding ----------------------
__global__ __launch_bounds__(256) void cvt_pad(const float* __restrict__ in,
                                               short* __restrict__ out,
                                               int kin, int kout) {
    long row = blockIdx.x;
    const float* src = in + row * (long)kin;
    short* dst = out + row * (long)kout;
    for (int c = threadIdx.x; c < kout; c += 256)
        dst[c] = (c < kin) ? f2bf(src[c]) : (short)0;
}

// ---------------- fast BT GEMM (all-bf16, async LDS staging) ---------------
// Y[m,n] = sum_k X[m,k] W[n,k] + bias[n]; 128x128 tile, BK=32,
// mfma 16x16x32 bf16; fused masked BN stats.
__global__ __launch_bounds__(256, 4)
void gemm_bt_bf16(const short* __restrict__ X, const short* __restrict__ W,
                  const float* __restrict__ bias, short* __restrict__ Y,
                  int N, int Kp, float* __restrict__ stats,
                  const int* __restrict__ lens, int Lshift)
{
    __shared__ short At[128 * 32];
    __shared__ short Bt[128 * 32];
    const int m0 = blockIdx.x * 128;
    const int n0 = blockIdx.y * 128;
    const int tid = threadIdx.x;
    const int w = tid >> 6, l = tid & 63;
    const int quad = l >> 4, l15 = l & 15;
    const int mo = (w & 1) * 64, no = (w >> 1) * 64;

    floatx4 acc[4][4];
#pragma unroll
    for (int i = 0; i < 4; i++)
#pragma unroll
        for (int j = 0; j < 4; j++) acc[i][j] = (floatx4){0.f, 0.f, 0.f, 0.f};

    const int srow = tid >> 2;        // 0..63
    const int sc8 = (tid & 3) * 8;    // 0,8,16,24
    const short* Xr0 = X + (long)(m0 + srow) * Kp + sc8;
    const short* Xr1 = X + (long)(m0 + 64 + srow) * Kp + sc8;
    const short* Wr0 = W + (long)(n0 + srow) * Kp + sc8;
    const short* Wr1 = W + (long)(n0 + 64 + srow) * Kp + sc8;
    short* At0 = At + tid * 8;            // lane-contiguous 16B slots
    short* At1 = At + 64 * 32 + tid * 8;
    short* Bt0 = Bt + tid * 8;
    short* Bt1 = Bt + 64 * 32 + tid * 8;

    for (int k0 = 0; k0 < Kp; k0 += 32) {
        __syncthreads();
        async_cp16(Xr0 + k0, At0);
        async_cp16(Xr1 + k0, At1);
        async_cp16(Wr0 + k0, Bt0);
        async_cp16(Wr1 + k0, Bt1);
        __syncthreads();
        short8 af[4], bfr[4];
#pragma unroll
        for (int i = 0; i < 4; i++) {
            af[i]  = *(const short8*)(At + (mo + i * 16 + l15) * 32 + quad * 8);
            bfr[i] = *(const short8*)(Bt + (no + i * 16 + l15) * 32 + quad * 8);
        }
#pragma unroll
        for (int i = 0; i < 4; i++)
#pragma unroll
            for (int j = 0; j < 4; j++)
                acc[i][j] = __builtin_amdgcn_mfma_f32_16x16x32_bf16(af[i], bfr[j], acc[i][j], 0, 0, 0);
    }

    const int Lmask = (1 << Lshift) - 1;
    float msk[4][4];
#pragma unroll
    for (int i = 0; i < 4; i++)
#pragma unroll
        for (int r = 0; r < 4; r++) {
            int rg = m0 + mo + i * 16 + quad * 4 + r;
            msk[i][r] = ((rg & Lmask) < lens[rg >> Lshift]) ? 1.f : 0.f;
        }
#pragma unroll
    for (int j = 0; j < 4; j++) {
        int colj = n0 + no + j * 16 + l15;
        float bv = bias[colj];
        float ps = 0.f, pss = 0.f;
#pragma unroll
        for (int i = 0; i < 4; i++)
#pragma unroll
            for (int r = 0; r < 4; r++) {
                int rg = m0 + mo + i * 16 + quad * 4 + r;
                float v = acc[i][j][r] + bv;
                Y[(long)rg * N + colj] = f2bf(v);
                ps += v * msk[i][r];
                pss += v * v * msk[i][r];
            }
        ps  += __shfl_xor(ps, 16, 64);  ps  += __shfl_xor(ps, 32, 64);
        pss += __shfl_xor(pss, 16, 64); pss += __shfl_xor(pss, 32, 64);
        if (l < 16) {
            atomicAdd(&stats[colj], ps);
            atomicAdd(&stats[N + colj], pss);
        }
    }
}

// ---------------- fallback BT GEMM (R1: fused fp32 cvt staging) ------------
template<bool XBF16, bool KAL>
__global__ __launch_bounds__(256, 2)
void gemm_bt(const void* __restrict__ Xp, const float* __restrict__ W,
             const float* __restrict__ bias, short* __restrict__ Y,
             int N, int Kin, int Kp, float* __restrict__ stats,
             const int* __restrict__ lens, int Lshift)
{
    __shared__ short At[128 * 32];
    __shared__ short Bt[128 * 32];
    const int m0 = blockIdx.x * 128;
    const int n0 = blockIdx.y * 128;
    const int tid = threadIdx.x;
    const int w = tid >> 6, l = tid & 63;
    const int quad = l >> 4, l15 = l & 15;
    const int mo = (w & 1) * 64, no = (w >> 1) * 64;

    floatx4 acc[4][4];
#pragma unroll
    for (int i = 0; i < 4; i++)
#pragma unroll
        for (int j = 0; j < 4; j++) acc[i][j] = (floatx4){0.f, 0.f, 0.f, 0.f};

    const int srow = tid >> 2;
    const int sc8 = (tid & 3) * 8;

    for (int k0 = 0; k0 < Kp; k0 += 32) {
        __syncthreads();
        const int c0 = k0 + sc8;
        short8 a0, a1, b0, b1;
        if (XBF16) {
            const short* X = (const short*)Xp;
            a0 = *(const short8*)(X + (long)(m0 + srow) * Kp + c0);
            a1 = *(const short8*)(X + (long)(m0 + 64 + srow) * Kp + c0);
        } else {
            const float* X = (const float*)Xp;
            if (KAL) {
                a0 = cvt8load(X + (long)(m0 + srow) * Kin + c0);
                a1 = cvt8load(X + (long)(m0 + 64 + srow) * Kin + c0);
            } else {
                a0 = cvt8guard(X + (long)(m0 + srow) * Kin, c0, Kin);
                a1 = cvt8guard(X + (long)(m0 + 64 + srow) * Kin, c0, Kin);
            }
        }
        if (KAL) {
            b0 = cvt8load(W + (long)(n0 + srow) * Kin + c0);
            b1 = cvt8load(W + (long)(n0 + 64 + srow) * Kin + c0);
        } else {
            b0 = cvt8guard(W + (long)(n0 + srow) * Kin, c0, Kin);
            b1 = cvt8guard(W + (long)(n0 + 64 + srow) * Kin, c0, Kin);
        }
        *(short8*)(At + srow * 32 + sc8) = a0;
        *(short8*)(At + (64 + srow) * 32 + sc8) = a1;
        *(short8*)(Bt + srow * 32 + sc8) = b0;
        *(short8*)(Bt + (64 + srow) * 32 + sc8) = b1;
        __syncthreads();
        short8 af[4], bfr[4];
#pragma unroll
        for (int i = 0; i < 4; i++) {
            af[i]  = *(const short8*)(At + (mo + i * 16 + l15) * 32 + quad * 8);
            bfr[i] = *(const short8*)(Bt + (no + i * 16 + l15) * 32 + quad * 8);
        }
#pragma unroll
        for (int i = 0; i < 4; i++)
#pragma unroll
            for (int j = 0; j < 4; j++)
                acc[i][j] = __builtin_amdgcn_mfma_f32_16x16x32_bf16(af[i], bfr[j], acc[i][j], 0, 0, 0);
    }

    const int Lmask = (1 << Lshift) - 1;
    float msk[4][4];
#pragma unroll
    for (int i = 0; i < 4; i++)
#pragma unroll
        for (int r = 0; r < 4; r++) {
            int rg = m0 + mo + i * 16 + quad * 4 + r;
            msk[i][r] = ((rg & Lmask) < lens[rg >> Lshift]) ? 1.f : 0.f;
        }
#pragma unroll
    for (int j = 0; j < 4; j++) {
        int colj = n0 + no + j * 16 + l15;
        float bv = bias[colj];
        float ps = 0.f, pss = 0.f;
#pragma unroll
        for (int i = 0; i < 4; i++)
#pragma unroll
            for (int r = 0; r < 4; r++) {
                int rg = m0 + mo + i * 16 + quad * 4 + r;
                float v = acc[i][j][r] + bv;
                Y[(long)rg * N + colj] = f2bf(v);
                ps += v * msk[i][r];
                pss += v * v * msk[i][r];
            }
        ps  += __shfl_xor(ps, 16, 64);  ps  += __shfl_xor(ps, 32, 64);
        pss += __shfl_xor(pss, 16, 64); pss += __shfl_xor(pss, 32, 64);
        if (l < 16) {
            atomicAdd(&stats[colj], ps);
            atomicAdd(&stats[N + colj], pss);
        }
    }
}

// ---------------- finalize: stats -> {scale, shift} per channel ------------
__global__ void finalize_stats(float* __restrict__ stats, const float* __restrict__ g,
                               const float* __restrict__ beta,
                               const int* __restrict__ lens, int C)
{
    __shared__ int lred[256];
    int t = threadIdx.x;
    if (t < 256) lred[t] = lens[t];
    __syncthreads();
    for (int s2 = 128; s2 > 0; s2 >>= 1) {
        if (t < s2) lred[t] += lred[t + s2];
        __syncthreads();
    }
    float cnt = (float)lred[0];
    if (t < C) {
        float mean = stats[t] / cnt;
        float var = fmaxf(stats[C + t] / cnt - mean * mean, 0.f);
        float a = rsqrtf(var + 1e-5f) * g[t];
        stats[t] = a;
        stats[C + t] = beta[t] - mean * a;
    }
}

// ---------------- BN + relu + row L2-normalize, C=512, in place ------------
__global__ __launch_bounds__(256)
void apply_norm512(short* __restrict__ Y, const float* __restrict__ stats)
{
    int w = threadIdx.x >> 6, l = threadIdx.x & 63;
    long row = (long)blockIdx.x * 4 + w;
    short8 yv = *(const short8*)(Y + row * 512 + l * 8);
    float v[8];
    float ss = 0.f;
#pragma unroll
    for (int i = 0; i < 8; i++) {
        int c = l * 8 + i;
        float t = fmaxf(bf2f(yv[i]) * stats[c] + stats[512 + c], 0.f);
        v[i] = t;
        ss += t * t;
    }
#pragma unroll
    for (int off = 1; off < 64; off <<= 1) ss += __shfl_xor(ss, off, 64);
    float scl = 1.f / fmaxf(sqrtf(ss), 1e-12f);
    short8 o;
#pragma unroll
    for (int i = 0; i < 8; i++) o[i] = f2bf(v[i] * scl);
    *(short8*)(Y + row * 512 + l * 8) = o;
}

// ---------------- v: BN + relu + L2norm, write transposed vT[s][d][b] ------
__global__ __launch_bounds__(256)
void apply_v_transpose(const short* __restrict__ Yv, short* __restrict__ vT,
                       const float* __restrict__ stats)
{
    __shared__ float post[16][513];
    __shared__ float partial[16][16];
    __shared__ float rss[16];
    int s = blockIdx.x >> 5;
    int b0 = (blockIdx.x & 31) * 16;
    int tid = threadIdx.x;
    int r = tid >> 4;
    int cg = tid & 15;
    const short* src = Yv + ((long)(s * 512 + b0 + r)) * 512;
    float ss = 0.f;
#pragma unroll
    for (int i = 0; i < 4; i++) {
        int c0 = i * 128 + cg * 8;
        short8 yv = *(const short8*)(src + c0);
#pragma unroll
        for (int j = 0; j < 8; j++) {
            int c = c0 + j;
            float t = fmaxf(bf2f(yv[j]) * stats[c] + stats[512 + c], 0.f);
            post[r][c] = t;
            ss += t * t;
        }
    }
    partial[r][cg] = ss;
    __syncthreads();
    if (tid < 16) {
        float tot = 0.f;
#pragma unroll
        for (int j = 0; j < 16; j++) tot += partial[tid][j];
        rss[tid] = 1.f / fmaxf(sqrtf(tot), 1e-12f);
    }
    __syncthreads();
    short* dst = vT + (long)s * 512 * 512 + b0;
    for (int e = tid; e < 512 * 16; e += 256) {
        int d = e >> 4, b = e & 15;
        dst[(long)d * 512 + b] = f2bf(post[b][d] * rss[b]);
    }
}

// ---------------- attention: per (s, 64 a-rows) block ----------------------
__global__ __launch_bounds__(256)
void attention(const short* __restrict__ q, const short* __restrict__ k,
               const short* __restrict__ vT, const int* __restrict__ b_lens,
               short* __restrict__ wv)
{
    __shared__ short tile[32 * 520];
    __shared__ short Pscr[4][16 * 40];
    const int s = blockIdx.y, a0 = blockIdx.x * 64;
    const int tid = threadIdx.x;
    const int w = tid >> 6, l = tid & 63;
    const int quad = l >> 4, l15 = l & 15;
    const int blen = b_lens[s];
    const int sr = tid >> 3;
    const int scg = (tid & 7) * 8;

    short8 qf[16];
    const short* qbase = q + ((long)(s * 128 + a0 + w * 16 + l15)) * 512 + quad * 8;
#pragma unroll
    for (int kk = 0; kk < 16; kk++) qf[kk] = *(const short8*)(qbase + kk * 32);

    floatx4 sc[32];
#pragma unroll
    for (int i = 0; i < 32; i++) sc[i] = (floatx4){0.f, 0.f, 0.f, 0.f};

    const short* kbase = k + (long)s * 512 * 512;
    for (int bt2 = 0; bt2 < 16; ++bt2) {
        __syncthreads();
        const short* krow = kbase + (long)(bt2 * 32 + sr) * 512;
#pragma unroll
        for (int i = 0; i < 2; i++) {
            short8 t0 = *(const short8*)(krow + i * 256 + scg);
            short8 t1 = *(const short8*)(krow + i * 256 + 64 + scg);
            short8 t2 = *(const short8*)(krow + i * 256 + 128 + scg);
            short8 t3 = *(const short8*)(krow + i * 256 + 192 + scg);
            *(short8*)(&tile[sr * 520 + i * 256 + scg]) = t0;
            *(short8*)(&tile[sr * 520 + i * 256 + 64 + scg]) = t1;
            *(short8*)(&tile[sr * 520 + i * 256 + 128 + scg]) = t2;
            *(short8*)(&tile[sr * 520 + i * 256 + 192 + scg]) = t3;
        }
        __syncthreads();
#pragma unroll
        for (int kk = 0; kk < 16; kk++) {
            short8 f0 = *(const short8*)(&tile[l15 * 520 + kk * 32 + quad * 8]);
            short8 f1 = *(const short8*)(&tile[(16 + l15) * 520 + kk * 32 + quad * 8]);
            sc[bt2 * 2]     = __builtin_amdgcn_mfma_f32_16x16x32_bf16(qf[kk], f0, sc[bt2 * 2], 0, 0, 0);
            sc[bt2 * 2 + 1] = __builtin_amdgcn_mfma_f32_16x16x32_bf16(qf[kk], f1, sc[bt2 * 2 + 1], 0, 0, 0);
        }
    }

    const float scaler = 6.25f;  // 1/(0.01*sqrt(256))
    float mrow[4] = {-__builtin_inff(), -__builtin_inff(), -__builtin_inff(), -__builtin_inff()};
#pragma unroll
    for (int bt = 0; bt < 32; ++bt) {
        bool valid = (bt * 16 + l15) < blen;
#pragma unroll
        for (int r = 0; r < 4; r++) {
            float v = valid ? sc[bt][r] * scaler : -__builtin_inff();
            sc[bt][r] = v;
            mrow[r] = fmaxf(mrow[r], v);
        }
    }
#pragma unroll
    for (int r = 0; r < 4; r++) {
#pragma unroll
        for (int off = 1; off < 16; off <<= 1)
            mrow[r] = fmaxf(mrow[r], __shfl_xor(mrow[r], off, 64));
    }
    float ssum[4] = {0.f, 0.f, 0.f, 0.f};
#pragma unroll
    for (int bt = 0; bt < 32; ++bt)
#pragma unroll
        for (int r = 0; r < 4; r++) {
            float p = __expf(sc[bt][r] - mrow[r]);
            sc[bt][r] = p;
            ssum[r] += p;
        }
#pragma unroll
    for (int r = 0; r < 4; r++) {
#pragma unroll
        for (int off = 1; off < 16; off <<= 1) ssum[r] += __shfl_xor(ssum[r], off, 64);
        ssum[r] = 1.f / ssum[r];
    }

    short8 pf[16];
    short* Pw = Pscr[w];
#pragma unroll
    for (int kk = 0; kk < 16; kk++) {
#pragma unroll
        for (int half = 0; half < 2; half++)
#pragma unroll
            for (int r = 0; r < 4; r++)
                Pw[(quad * 4 + r) * 40 + half * 16 + l15] = f2bf(sc[kk * 2 + half][r] * ssum[r]);
        pf[kk] = *(const short8*)(&Pw[l15 * 40 + quad * 8]);
    }

    const short* vbase = vT + (long)s * 512 * 512;
    short* wvbase = wv + ((long)(s * 128 + a0 + w * 16 + quad * 4)) * 512;
    for (int dt = 0; dt < 16; ++dt) {
        __syncthreads();
        const short* vrow = vbase + (long)(dt * 32 + sr) * 512;
#pragma unroll
        for (int i = 0; i < 2; i++) {
            short8 t0 = *(const short8*)(vrow + i * 256 + scg);
            short8 t1 = *(const short8*)(vrow + i * 256 + 64 + scg);
            short8 t2 = *(const short8*)(vrow + i * 256 + 128 + scg);
            short8 t3 = *(const short8*)(vrow + i * 256 + 192 + scg);
            *(short8*)(&tile[sr * 520 + i * 256 + scg]) = t0;
            *(short8*)(&tile[sr * 520 + i * 256 + 64 + scg]) = t1;
            *(short8*)(&tile[sr * 520 + i * 256 + 128 + scg]) = t2;
            *(short8*)(&tile[sr * 520 + i * 256 + 192 + scg]) = t3;
        }
        __syncthreads();
        floatx4 o0 = (floatx4){0.f, 0.f, 0.f, 0.f};
        floatx4 o1 = (floatx4){0.f, 0.f, 0.f, 0.f};
#pragma unroll
        for (int kk = 0; kk < 16; kk++) {
            short8 f0 = *(const short8*)(&tile[l15 * 520 + kk * 32 + quad * 8]);
            short8 f1 = *(const short8*)(&tile[(16 + l15) * 520 + kk * 32 + quad * 8]);
            o0 = __builtin_amdgcn_mfma_f32_16x16x32_bf16(pf[kk], f0, o0, 0, 0, 0);
            o1 = __builtin_amdgcn_mfma_f32_16x16x32_bf16(pf[kk], f1, o1, 0, 0, 0);
        }
#pragma unroll
        for (int r = 0; r < 4; r++) {
            wvbase[(long)r * 512 + dt * 32 + l15]      = f2bf(o0[r]);
            wvbase[(long)r * 512 + dt * 32 + 16 + l15] = f2bf(o1[r]);
        }
    }
}

// ---------------- f: BN + relu + mask_a -> d_out fp32 ----------------------
__global__ __launch_bounds__(256)
void apply_f(const short* __restrict__ Yf, const float* __restrict__ stats,
             const int* __restrict__ a_lens, float* __restrict__ out)
{
    const long total = (long)32768 * 256;
    for (long e = (long)blockIdx.x * 256 + threadIdx.x; e < total; e += (long)gridDim.x * 256) {
        int c = (int)(e & 255);
        long row = e >> 8;
        int sI = (int)(row >> 7), pos = (int)(row & 127);
        float v = fmaxf(bf2f(Yf[e]) * stats[c] + stats[256 + c], 0.f);
        out[e] = (pos < a_lens[sI]) ? v : 0.f;
    }
}

// ---------------------------------------------------------------------------
extern "C" void kernel_launch(void* const* d_in, const int* in_sizes, int n_in,
                              void* d_out, int out_size, void* d_ws, size_t ws_size,
                              hipStream_t stream)
{
    (void)in_sizes; (void)n_in; (void)out_size;
    const float* A     = (const float*)d_in[0];
    const float* B     = (const float*)d_in[1];
    const int* a_lens  = (const int*)d_in[2];
    const int* b_lens  = (const int*)d_in[3];
    const float* Wq    = (const float*)d_in[4];
    const float* bq    = (const float*)d_in[5];
    const float* gq    = (const float*)d_in[6];
    const float* betaq = (const float*)d_in[7];
    const float* Wk    = (const float*)d_in[8];
    const float* bk    = (const float*)d_in[9];
    const float* gk    = (const float*)d_in[10];
    const float* betak = (const float*)d_in[11];
    const float* Wv    = (const float*)d_in[12];
    const float* bv    = (const float*)d_in[13];
    const float* gv    = (const float*)d_in[14];
    const float* betav = (const float*)d_in[15];
    const float* Wf    = (const float*)d_in[16];
    const float* bfp   = (const float*)d_in[17];
    const float* gf    = (const float*)d_in[18];
    const float* betaf = (const float*)d_in[19];
    float* out = (float*)d_out;
    char* base = (char*)d_ws;

    // ---- fast layout (needs ~395.4 MB) ----
    const size_t oAbf = 0;                      // 16.8M, dead after q-gemm
    const size_t oWqb = oAbf + 16777216;        // weights (persistent, ~1.2M)
    const size_t oWkb = oWqb + 262144;
    const size_t oWvb = oWkb + 294912;
    const size_t oWfb = oWvb + 294912;
    const size_t oBbf = oWfb + 262144;          // 75.5M, dead after k-gemm
    const size_t oQb  = oBbf + 75497472;        // 33.6M q
    const size_t oKb  = oQb + 33554432;         // 134.2M Yv then kb
    const size_t oVT  = oKb + 134217728;        // 134.2M vT
    const size_t oSt  = oVT + 134217728;        // 16K stats
    const size_t FAST_NEED = oSt + 16384;

    if (ws_size >= FAST_NEED) {
        short* Abf = (short*)(base + oAbf);
        short* Wqb = (short*)(base + oWqb);
        short* Wkb = (short*)(base + oWkb);
        short* Wvb = (short*)(base + oWvb);
        short* Wfb = (short*)(base + oWfb);
        short* Bbf = (short*)(base + oBbf);
        short* qb  = (short*)(base + oQb);
        short* YvKb = (short*)(base + oKb);
        short* vT  = (short*)(base + oVT);
        short* wvb = (short*)(base + oBbf);     // reuses Bbf after k-gemm
        short* Yf  = (short*)(base + oQb);      // reuses qb after attention
        float* stQ = (float*)(base + oSt);
        float* stK = stQ + 1024;
        float* stV = stQ + 2048;
        float* stF = stQ + 3072;

        hipMemsetAsync(stQ, 0, 16384, stream);

        // convert all GEMM operands to bf16 (K padded 265->288)
        cvt_pad<<<32768, 256, 0, stream>>>(A, Abf, 256, 256);
        cvt_pad<<<131072, 256, 0, stream>>>(B, Bbf, 265, 288);
        cvt_pad<<<512, 256, 0, stream>>>(Wq, Wqb, 256, 256);
        cvt_pad<<<512, 256, 0, stream>>>(Wk, Wkb, 265, 288);
        cvt_pad<<<512, 256, 0, stream>>>(Wv, Wvb, 265, 288);
        cvt_pad<<<256, 256, 0, stream>>>(Wf, Wfb, 512, 512);

        // q projection
        gemm_bt_bf16<<<dim3(256, 4), 256, 0, stream>>>(
            Abf, Wqb, bq, qb, 512, 256, stQ, a_lens, 7);
        // v projection -> Yv (in kb region)
        gemm_bt_bf16<<<dim3(1024, 4), 256, 0, stream>>>(
            Bbf, Wvb, bv, YvKb, 512, 288, stV, b_lens, 9);
        finalize_stats<<<1, 512, 0, stream>>>(stV, gv, betav, b_lens, 512);
        apply_v_transpose<<<8192, 256, 0, stream>>>(YvKb, vT, stV);
        // k projection (overwrites Yv region)
        gemm_bt_bf16<<<dim3(1024, 4), 256, 0, stream>>>(
            Bbf, Wkb, bk, YvKb, 512, 288, stK, b_lens, 9);
        finalize_stats<<<1, 512, 0, stream>>>(stK, gk, betak, b_lens, 512);
        apply_norm512<<<32768, 256, 0, stream>>>(YvKb, stK);
        finalize_stats<<<1, 512, 0, stream>>>(stQ, gq, betaq, a_lens, 512);
        apply_norm512<<<8192, 256, 0, stream>>>(qb, stQ);

        attention<<<dim3(2, 256), 256, 0, stream>>>(qb, YvKb, vT, b_lens, wvb);

        gemm_bt_bf16<<<dim3(256, 2), 256, 0, stream>>>(
            wvb, Wfb, bfp, Yf, 256, 512, stF, a_lens, 7);
        finalize_stats<<<1, 512, 0, stream>>>(stF, gf, betaf, a_lens, 256);
        apply_f<<<8192, 256, 0, stream>>>(Yf, stF, a_lens, out);
        return;
    }

    // ---- fallback: R1 layout/path (peak ~335.6 MB, known correct) ----
    short* qb  = (short*)(base);
    short* Yv  = (short*)(base + 33554432);
    short* kb  = Yv;
    short* vT  = (short*)(base + 33554432 + 134217728);
    short* wvb = (short*)(base + 33554432 + 2L * 134217728);
    float* stQ = (float*)(base + 2L * 33554432 + 2L * 134217728);
    float* stK = stQ + 1024;
    float* stV = stQ + 2048;
    float* stF = stQ + 3072;
    short* Yf  = qb;

    hipMemsetAsync(stQ, 0, 16384, stream);

    gemm_bt<false, true><<<dim3(256, 4), 256, 0, stream>>>(
        A, Wq, bq, qb, 512, 256, 256, stQ, a_lens, 7);
    gemm_bt<false, false><<<dim3(1024, 4), 256, 0, stream>>>(
        B, Wv, bv, Yv, 512, 265, 288, stV, b_lens, 9);
    finalize_stats<<<1, 512, 0, stream>>>(stV, gv, betav, b_lens, 512);
    apply_v_transpose<<<8192, 256, 0, stream>>>(Yv, vT, stV);
    gemm_bt<false, false><<<dim3(1024, 4), 256, 0, stream>>>(
        B, Wk, bk, kb, 512, 265, 288, stK, b_lens, 9);
    finalize_stats<<<1, 512, 0, stream>>>(stK, gk, betak, b_lens, 512);
    apply_norm512<<<32768, 256, 0, stream>>>(kb, stK);
    finalize_stats<<<1, 512, 0, stream>>>(stQ, gq, betaq, a_lens, 512);
    apply_norm512<<<8192, 256, 0, stream>>>(qb, stQ);
    attention<<<dim3(2, 256), 256, 0, stream>>>(qb, kb, vT, b_lens, wvb);
    gemm_bt<true, true><<<dim3(256, 2), 256, 0, stream>>>(
        wvb, Wf, bfp, Yf, 256, 512, 512, stF, a_lens, 7);
    finalize_stats<<<1, 512, 0, stream>>>(stF, gf, betaf, a_lens, 256);
    apply_f<<<8192, 256, 0, stream>>>(Yf, stF, a_lens, out);
}

// Round 4
// 1040.843 us; speedup vs baseline: 1.7924x; 1.0082x over previous
//
#include <hip/hip_runtime.h>
#include <hip/hip_bf16.h>
#include <stdint.h>

// ---------------------------------------------------------------------------
// AttentionBlock: q/k/v ctx-proj (GEMM + masked-BN + relu + L2norm), attention
// (QK^T -> masked softmax -> PV), f ctx-proj (GEMM + masked-BN + relu), masked.
// Fast path: bf16 operands (K padded to mult of 96), GEMM BK=96 (3 iters for
// K=288), async global_load_lds staging, LDS-staged coalesced C writes.
// Fallback (small ws): R1 path, known correct.
// ---------------------------------------------------------------------------

typedef __attribute__((ext_vector_type(8))) short short8;
typedef __attribute__((ext_vector_type(4))) float floatx4;

__device__ __forceinline__ float bf2f(short h) {
    union { unsigned u; float f; } c;
    c.u = ((unsigned)(unsigned short)h) << 16;
    return c.f;
}
__device__ __forceinline__ short f2bf(float f) {
    union { float f; unsigned u; } c;
    c.f = f;
    unsigned u = c.u + 0x7fffu + ((c.u >> 16) & 1u);  // RNE
    return (short)(u >> 16);
}

__device__ __forceinline__ void async_cp16(const short* g, short* l) {
    __builtin_amdgcn_global_load_lds(
        (const __attribute__((address_space(1))) unsigned int*)g,
        (__attribute__((address_space(3))) unsigned int*)l, 16, 0, 0);
}

__device__ __forceinline__ short8 cvt8load(const float* p) {
    float4 f0 = *(const float4*)(p);
    float4 f1 = *(const float4*)(p + 4);
    short8 r;
    r[0] = f2bf(f0.x); r[1] = f2bf(f0.y); r[2] = f2bf(f0.z); r[3] = f2bf(f0.w);
    r[4] = f2bf(f1.x); r[5] = f2bf(f1.y); r[6] = f2bf(f1.z); r[7] = f2bf(f1.w);
    return r;
}
__device__ __forceinline__ short8 cvt8guard(const float* row, int c0, int Kin) {
    short8 r;
#pragma unroll
    for (int j = 0; j < 8; j++) {
        int c = c0 + j;
        r[j] = (c < Kin) ? f2bf(row[c]) : (short)0;
    }
    return r;
}

// ---------------- convert fp32 -> bf16 with K padding ----------------------
__global__ __launch_bounds__(256) void cvt_pad(const float* __restrict__ in,
                                               short* __restrict__ out,
                                               int kin, int kout) {
    long row = blockIdx.x;
    const float* src = in + row * (long)kin;
    short* dst = out + row * (long)kout;
    for (int c = threadIdx.x; c < kout; c += 256)
        dst[c] = (c < kin) ? f2bf(src[c]) : (short)0;
}

// ---------------- fast BT GEMM: BK=96, async staging, LDS epilogue ---------
// Y[m,n] = sum_k X[m,k] W[n,k] + bias[n]; 128x128 tile; Kp % 96 == 0.
// Fused masked BN stats (sum/sumsq over valid rows).
__global__ __launch_bounds__(256, 4)
void gemm_bt96(const short* __restrict__ X, const short* __restrict__ W,
               const float* __restrict__ bias, short* __restrict__ Y,
               int N, int Kp, float* __restrict__ stats,
               const int* __restrict__ lens, int Lshift)
{
    __shared__ short SH[128 * 96 * 2];   // At | Bt ; reused as C-stage 128x132
    short* At = SH;
    short* Bt = SH + 128 * 96;
    const int m0 = blockIdx.x * 128;
    const int n0 = blockIdx.y * 128;
    const int tid = threadIdx.x;
    const int l = tid & 63, w = tid >> 6;
    const int quad = l >> 4, l15 = l & 15;
    const int mo = (w & 1) * 64, no = (w >> 1) * 64;

    floatx4 acc[4][4];
#pragma unroll
    for (int i = 0; i < 4; i++)
#pragma unroll
        for (int j = 0; j < 4; j++) acc[i][j] = (floatx4){0.f, 0.f, 0.f, 0.f};

    // staging element-offsets (identical for A and B tiles; B = A + delta)
    int offA[6];
#pragma unroll
    for (int c = 0; c < 6; c++) {
        unsigned e = c * 2048u + (unsigned)tid * 8u;   // short index in 128x96 tile
        unsigned row = e / 96u;
        unsigned col = e - row * 96u;
        offA[c] = (int)((unsigned)(m0 + row) * (unsigned)Kp + col);
    }
    const int dB = (n0 - m0) * Kp;

    for (int k0 = 0; k0 < Kp; k0 += 96) {
        __syncthreads();
#pragma unroll
        for (int c = 0; c < 6; c++) {
            async_cp16(X + offA[c] + k0, At + c * 2048 + tid * 8);
            async_cp16(W + offA[c] + dB + k0, Bt + c * 2048 + tid * 8);
        }
        __syncthreads();
#pragma unroll
        for (int seg = 0; seg < 3; seg++) {
            short8 af[4], bfr[4];
#pragma unroll
            for (int i = 0; i < 4; i++) {
                af[i]  = *(const short8*)(At + (mo + i * 16 + l15) * 96 + seg * 32 + quad * 8);
                bfr[i] = *(const short8*)(Bt + (no + i * 16 + l15) * 96 + seg * 32 + quad * 8);
            }
#pragma unroll
            for (int i = 0; i < 4; i++)
#pragma unroll
                for (int j = 0; j < 4; j++)
                    acc[i][j] = __builtin_amdgcn_mfma_f32_16x16x32_bf16(af[i], bfr[j], acc[i][j], 0, 0, 0);
        }
    }

    // ---- epilogue: bias + masked stats + LDS-staged coalesced store ----
    __syncthreads();                     // all waves done reading At/Bt
    const int Lmask = (1 << Lshift) - 1;
    float msk[4][4];
#pragma unroll
    for (int i = 0; i < 4; i++)
#pragma unroll
        for (int r = 0; r < 4; r++) {
            int rg = m0 + mo + i * 16 + quad * 4 + r;
            msk[i][r] = ((rg & Lmask) < lens[rg >> Lshift]) ? 1.f : 0.f;
        }
    short* Cs = SH;                      // 128 rows, stride 132 (16896 <= 24576)
#pragma unroll
    for (int j = 0; j < 4; j++) {
        int coll = no + j * 16 + l15;    // tile-local col
        float bv = bias[n0 + coll];
        float ps = 0.f, pss = 0.f;
#pragma unroll
        for (int i = 0; i < 4; i++)
#pragma unroll
            for (int r = 0; r < 4; r++) {
                int rl = mo + i * 16 + quad * 4 + r;
                float v = acc[i][j][r] + bv;
                Cs[rl * 132 + coll] = f2bf(v);
                ps += v * msk[i][r];
                pss += v * v * msk[i][r];
            }
        ps  += __shfl_xor(ps, 16, 64);  ps  += __shfl_xor(ps, 32, 64);
        pss += __shfl_xor(pss, 16, 64); pss += __shfl_xor(pss, 32, 64);
        if (l < 16) {
            atomicAdd(&stats[n0 + coll], ps);
            atomicAdd(&stats[N + n0 + coll], pss);
        }
    }
    __syncthreads();
#pragma unroll
    for (int c = 0; c < 8; c++) {
        int e = c * 2048 + tid * 8;      // 128*128 tile, row-major
        int row = e >> 7, col = e & 127;
        short8 vv = *(const short8*)(Cs + row * 132 + col);
        *(short8*)(Y + (long)(m0 + row) * N + n0 + col) = vv;
    }
}

// ---------------- fallback BT GEMM (R1: fused fp32 cvt staging) ------------
template<bool XBF16, bool KAL>
__global__ __launch_bounds__(256, 2)
void gemm_bt(const void* __restrict__ Xp, const float* __restrict__ W,
             const float* __restrict__ bias, short* __restrict__ Y,
             int N, int Kin, int Kp, float* __restrict__ stats,
             const int* __restrict__ lens, int Lshift)
{
    __shared__ short At[128 * 32];
    __shared__ short Bt[128 * 32];
    const int m0 = blockIdx.x * 128;
    const int n0 = blockIdx.y * 128;
    const int tid = threadIdx.x;
    const int w = tid >> 6, l = tid & 63;
    const int quad = l >> 4, l15 = l & 15;
    const int mo = (w & 1) * 64, no = (w >> 1) * 64;

    floatx4 acc[4][4];
#pragma unroll
    for (int i = 0; i < 4; i++)
#pragma unroll
        for (int j = 0; j < 4; j++) acc[i][j] = (floatx4){0.f, 0.f, 0.f, 0.f};

    const int srow = tid >> 2;
    const int sc8 = (tid & 3) * 8;

    for (int k0 = 0; k0 < Kp; k0 += 32) {
        __syncthreads();
        const int c0 = k0 + sc8;
        short8 a0, a1, b0, b1;
        if (XBF16) {
            const short* X = (const short*)Xp;
            a0 = *(const short8*)(X + (long)(m0 + srow) * Kp + c0);
            a1 = *(const short8*)(X + (long)(m0 + 64 + srow) * Kp + c0);
        } else {
            const float* X = (const float*)Xp;
            if (KAL) {
                a0 = cvt8load(X + (long)(m0 + srow) * Kin + c0);
                a1 = cvt8load(X + (long)(m0 + 64 + srow) * Kin + c0);
            } else {
                a0 = cvt8guard(X + (long)(m0 + srow) * Kin, c0, Kin);
                a1 = cvt8guard(X + (long)(m0 + 64 + srow) * Kin, c0, Kin);
            }
        }
        if (KAL) {
            b0 = cvt8load(W + (long)(n0 + srow) * Kin + c0);
            b1 = cvt8load(W + (long)(n0 + 64 + srow) * Kin + c0);
        } else {
            b0 = cvt8guard(W + (long)(n0 + srow) * Kin, c0, Kin);
            b1 = cvt8guard(W + (long)(n0 + 64 + srow) * Kin, c0, Kin);
        }
        *(short8*)(At + srow * 32 + sc8) = a0;
        *(short8*)(At + (64 + srow) * 32 + sc8) = a1;
        *(short8*)(Bt + srow * 32 + sc8) = b0;
        *(short8*)(Bt + (64 + srow) * 32 + sc8) = b1;
        __syncthreads();
        short8 af[4], bfr[4];
#pragma unroll
        for (int i = 0; i < 4; i++) {
            af[i]  = *(const short8*)(At + (mo + i * 16 + l15) * 32 + quad * 8);
            bfr[i] = *(const short8*)(Bt + (no + i * 16 + l15) * 32 + quad * 8);
        }
#pragma unroll
        for (int i = 0; i < 4; i++)
#pragma unroll
            for (int j = 0; j < 4; j++)
                acc[i][j] = __builtin_amdgcn_mfma_f32_16x16x32_bf16(af[i], bfr[j], acc[i][j], 0, 0, 0);
    }

    const int Lmask = (1 << Lshift) - 1;
    float msk[4][4];
#pragma unroll
    for (int i = 0; i < 4; i++)
#pragma unroll
        for (int r = 0; r < 4; r++) {
            int rg = m0 + mo + i * 16 + quad * 4 + r;
            msk[i][r] = ((rg & Lmask) < lens[rg >> Lshift]) ? 1.f : 0.f;
        }
#pragma unroll
    for (int j = 0; j < 4; j++) {
        int colj = n0 + no + j * 16 + l15;
        float bv = bias[colj];
        float ps = 0.f, pss = 0.f;
#pragma unroll
        for (int i = 0; i < 4; i++)
#pragma unroll
            for (int r = 0; r < 4; r++) {
                int rg = m0 + mo + i * 16 + quad * 4 + r;
                float v = acc[i][j][r] + bv;
                Y[(long)rg * N + colj] = f2bf(v);
                ps += v * msk[i][r];
                pss += v * v * msk[i][r];
            }
        ps  += __shfl_xor(ps, 16, 64);  ps  += __shfl_xor(ps, 32, 64);
        pss += __shfl_xor(pss, 16, 64); pss += __shfl_xor(pss, 32, 64);
        if (l < 16) {
            atomicAdd(&stats[colj], ps);
            atomicAdd(&stats[N + colj], pss);
        }
    }
}

// ---------------- finalize: stats -> {scale, shift} per channel ------------
__global__ void finalize_stats(float* __restrict__ stats, const float* __restrict__ g,
                               const float* __restrict__ beta,
                               const int* __restrict__ lens, int C)
{
    __shared__ int lred[256];
    int t = threadIdx.x;
    if (t < 256) lred[t] = lens[t];
    __syncthreads();
    for (int s2 = 128; s2 > 0; s2 >>= 1) {
        if (t < s2) lred[t] += lred[t + s2];
        __syncthreads();
    }
    float cnt = (float)lred[0];
    if (t < C) {
        float mean = stats[t] / cnt;
        float var = fmaxf(stats[C + t] / cnt - mean * mean, 0.f);
        float a = rsqrtf(var + 1e-5f) * g[t];
        stats[t] = a;
        stats[C + t] = beta[t] - mean * a;
    }
}

// ---------------- BN + relu + row L2-normalize, C=512, in place ------------
__global__ __launch_bounds__(256)
void apply_norm512(short* __restrict__ Y, const float* __restrict__ stats)
{
    int w = threadIdx.x >> 6, l = threadIdx.x & 63;
    long row = (long)blockIdx.x * 4 + w;
    short8 yv = *(const short8*)(Y + row * 512 + l * 8);
    float v[8];
    float ss = 0.f;
#pragma unroll
    for (int i = 0; i < 8; i++) {
        int c = l * 8 + i;
        float t = fmaxf(bf2f(yv[i]) * stats[c] + stats[512 + c], 0.f);
        v[i] = t;
        ss += t * t;
    }
#pragma unroll
    for (int off = 1; off < 64; off <<= 1) ss += __shfl_xor(ss, off, 64);
    float scl = 1.f / fmaxf(sqrtf(ss), 1e-12f);
    short8 o;
#pragma unroll
    for (int i = 0; i < 8; i++) o[i] = f2bf(v[i] * scl);
    *(short8*)(Y + row * 512 + l * 8) = o;
}

// ---------------- v: BN + relu + L2norm, write transposed vT[s][d][b] ------
__global__ __launch_bounds__(256)
void apply_v_transpose(const short* __restrict__ Yv, short* __restrict__ vT,
                       const float* __restrict__ stats)
{
    __shared__ float post[16][513];
    __shared__ float partial[16][16];
    __shared__ float rss[16];
    int s = blockIdx.x >> 5;
    int b0 = (blockIdx.x & 31) * 16;
    int tid = threadIdx.x;
    int r = tid >> 4;
    int cg = tid & 15;
    const short* src = Yv + ((long)(s * 512 + b0 + r)) * 512;
    float ss = 0.f;
#pragma unroll
    for (int i = 0; i < 4; i++) {
        int c0 = i * 128 + cg * 8;
        short8 yv = *(const short8*)(src + c0);
#pragma unroll
        for (int j = 0; j < 8; j++) {
            int c = c0 + j;
            float t = fmaxf(bf2f(yv[j]) * stats[c] + stats[512 + c], 0.f);
            post[r][c] = t;
            ss += t * t;
        }
    }
    partial[r][cg] = ss;
    __syncthreads();
    if (tid < 16) {
        float tot = 0.f;
#pragma unroll
        for (int j = 0; j < 16; j++) tot += partial[tid][j];
        rss[tid] = 1.f / fmaxf(sqrtf(tot), 1e-12f);
    }
    __syncthreads();
    short* dst = vT + (long)s * 512 * 512 + b0;
    for (int e = tid; e < 512 * 16; e += 256) {
        int d = e >> 4, b = e & 15;
        dst[(long)d * 512 + b] = f2bf(post[b][d] * rss[b]);
    }
}

// ---------------- attention: per (s, 64 a-rows) block ----------------------
__global__ __launch_bounds__(256)
void attention(const short* __restrict__ q, const short* __restrict__ k,
               const short* __restrict__ vT, const int* __restrict__ b_lens,
               short* __restrict__ wv, int wvStride)
{
    __shared__ short tile[32 * 520];
    __shared__ short Pscr[4][16 * 40];
    const int s = blockIdx.y, a0 = blockIdx.x * 64;
    const int tid = threadIdx.x;
    const int w = tid >> 6, l = tid & 63;
    const int quad = l >> 4, l15 = l & 15;
    const int blen = b_lens[s];
    const int sr = tid >> 3;
    const int scg = (tid & 7) * 8;

    short8 qf[16];
    const short* qbase = q + ((long)(s * 128 + a0 + w * 16 + l15)) * 512 + quad * 8;
#pragma unroll
    for (int kk = 0; kk < 16; kk++) qf[kk] = *(const short8*)(qbase + kk * 32);

    floatx4 sc[32];
#pragma unroll
    for (int i = 0; i < 32; i++) sc[i] = (floatx4){0.f, 0.f, 0.f, 0.f};

    const short* kbase = k + (long)s * 512 * 512;
    for (int bt2 = 0; bt2 < 16; ++bt2) {
        __syncthreads();
        const short* krow = kbase + (long)(bt2 * 32 + sr) * 512;
#pragma unroll
        for (int i = 0; i < 2; i++) {
            short8 t0 = *(const short8*)(krow + i * 256 + scg);
            short8 t1 = *(const short8*)(krow + i * 256 + 64 + scg);
            short8 t2 = *(const short8*)(krow + i * 256 + 128 + scg);
            short8 t3 = *(const short8*)(krow + i * 256 + 192 + scg);
            *(short8*)(&tile[sr * 520 + i * 256 + scg]) = t0;
            *(short8*)(&tile[sr * 520 + i * 256 + 64 + scg]) = t1;
            *(short8*)(&tile[sr * 520 + i * 256 + 128 + scg]) = t2;
            *(short8*)(&tile[sr * 520 + i * 256 + 192 + scg]) = t3;
        }
        __syncthreads();
#pragma unroll
        for (int kk = 0; kk < 16; kk++) {
            short8 f0 = *(const short8*)(&tile[l15 * 520 + kk * 32 + quad * 8]);
            short8 f1 = *(const short8*)(&tile[(16 + l15) * 520 + kk * 32 + quad * 8]);
            sc[bt2 * 2]     = __builtin_amdgcn_mfma_f32_16x16x32_bf16(qf[kk], f0, sc[bt2 * 2], 0, 0, 0);
            sc[bt2 * 2 + 1] = __builtin_amdgcn_mfma_f32_16x16x32_bf16(qf[kk], f1, sc[bt2 * 2 + 1], 0, 0, 0);
        }
    }

    const float scaler = 6.25f;  // 1/(0.01*sqrt(256))
    float mrow[4] = {-__builtin_inff(), -__builtin_inff(), -__builtin_inff(), -__builtin_inff()};
#pragma unroll
    for (int bt = 0; bt < 32; ++bt) {
        bool valid = (bt * 16 + l15) < blen;
#pragma unroll
        for (int r = 0; r < 4; r++) {
            float v = valid ? sc[bt][r] * scaler : -__builtin_inff();
            sc[bt][r] = v;
            mrow[r] = fmaxf(mrow[r], v);
        }
    }
#pragma unroll
    for (int r = 0; r < 4; r++) {
#pragma unroll
        for (int off = 1; off < 16; off <<= 1)
            mrow[r] = fmaxf(mrow[r], __shfl_xor(mrow[r], off, 64));
    }
    float ssum[4] = {0.f, 0.f, 0.f, 0.f};
#pragma unroll
    for (int bt = 0; bt < 32; ++bt)
#pragma unroll
        for (int r = 0; r < 4; r++) {
            float p = __expf(sc[bt][r] - mrow[r]);
            sc[bt][r] = p;
            ssum[r] += p;
        }
#pragma unroll
    for (int r = 0; r < 4; r++) {
#pragma unroll
        for (int off = 1; off < 16; off <<= 1) ssum[r] += __shfl_xor(ssum[r], off, 64);
        ssum[r] = 1.f / ssum[r];
    }

    short8 pf[16];
    short* Pw = Pscr[w];
#pragma unroll
    for (int kk = 0; kk < 16; kk++) {
#pragma unroll
        for (int half = 0; half < 2; half++)
#pragma unroll
            for (int r = 0; r < 4; r++)
                Pw[(quad * 4 + r) * 40 + half * 16 + l15] = f2bf(sc[kk * 2 + half][r] * ssum[r]);
        pf[kk] = *(const short8*)(&Pw[l15 * 40 + quad * 8]);
    }

    const short* vbase = vT + (long)s * 512 * 512;
    short* wvbase = wv + (long)(s * 128 + a0 + w * 16 + quad * 4) * wvStride;
    for (int dt = 0; dt < 16; ++dt) {
        __syncthreads();
        const short* vrow = vbase + (long)(dt * 32 + sr) * 512;
#pragma unroll
        for (int i = 0; i < 2; i++) {
            short8 t0 = *(const short8*)(vrow + i * 256 + scg);
            short8 t1 = *(const short8*)(vrow + i * 256 + 64 + scg);
            short8 t2 = *(const short8*)(vrow + i * 256 + 128 + scg);
            short8 t3 = *(const short8*)(vrow + i * 256 + 192 + scg);
            *(short8*)(&tile[sr * 520 + i * 256 + scg]) = t0;
            *(short8*)(&tile[sr * 520 + i * 256 + 64 + scg]) = t1;
            *(short8*)(&tile[sr * 520 + i * 256 + 128 + scg]) = t2;
            *(short8*)(&tile[sr * 520 + i * 256 + 192 + scg]) = t3;
        }
        __syncthreads();
        floatx4 o0 = (floatx4){0.f, 0.f, 0.f, 0.f};
        floatx4 o1 = (floatx4){0.f, 0.f, 0.f, 0.f};
#pragma unroll
        for (int kk = 0; kk < 16; kk++) {
            short8 f0 = *(const short8*)(&tile[l15 * 520 + kk * 32 + quad * 8]);
            short8 f1 = *(const short8*)(&tile[(16 + l15) * 520 + kk * 32 + quad * 8]);
            o0 = __builtin_amdgcn_mfma_f32_16x16x32_bf16(pf[kk], f0, o0, 0, 0, 0);
            o1 = __builtin_amdgcn_mfma_f32_16x16x32_bf16(pf[kk], f1, o1, 0, 0, 0);
        }
#pragma unroll
        for (int r = 0; r < 4; r++) {
            wvbase[(long)r * wvStride + dt * 32 + l15]      = f2bf(o0[r]);
            wvbase[(long)r * wvStride + dt * 32 + 16 + l15] = f2bf(o1[r]);
        }
    }
}

// ---------------- f: BN + relu + mask_a -> d_out fp32 ----------------------
__global__ __launch_bounds__(256)
void apply_f(const short* __restrict__ Yf, const float* __restrict__ stats,
             const int* __restrict__ a_lens, float* __restrict__ out)
{
    const long total = (long)32768 * 256;
    for (long e = (long)blockIdx.x * 256 + threadIdx.x; e < total; e += (long)gridDim.x * 256) {
        int c = (int)(e & 255);
        long row = e >> 8;
        int sI = (int)(row >> 7), pos = (int)(row & 127);
        float v = fmaxf(bf2f(Yf[e]) * stats[c] + stats[256 + c], 0.f);
        out[e] = (pos < a_lens[sI]) ? v : 0.f;
    }
}

// ---------------------------------------------------------------------------
extern "C" void kernel_launch(void* const* d_in, const int* in_sizes, int n_in,
                              void* d_out, int out_size, void* d_ws, size_t ws_size,
                              hipStream_t stream)
{
    (void)in_sizes; (void)n_in; (void)out_size;
    const float* A     = (const float*)d_in[0];
    const float* B     = (const float*)d_in[1];
    const int* a_lens  = (const int*)d_in[2];
    const int* b_lens  = (const int*)d_in[3];
    const float* Wq    = (const float*)d_in[4];
    const float* bq    = (const float*)d_in[5];
    const float* gq    = (const float*)d_in[6];
    const float* betaq = (const float*)d_in[7];
    const float* Wk    = (const float*)d_in[8];
    const float* bk    = (const float*)d_in[9];
    const float* gk    = (const float*)d_in[10];
    const float* betak = (const float*)d_in[11];
    const float* Wv    = (const float*)d_in[12];
    const float* bv    = (const float*)d_in[13];
    const float* gv    = (const float*)d_in[14];
    const float* betav = (const float*)d_in[15];
    const float* Wf    = (const float*)d_in[16];
    const float* bfp   = (const float*)d_in[17];
    const float* gf    = (const float*)d_in[18];
    const float* betaf = (const float*)d_in[19];
    float* out = (float*)d_out;
    char* base = (char*)d_ws;

    // ---- fast layout (378.7 MB; proven ws >= 395.4 MB takes this path) ----
    const size_t oWqb = 0;                         // 512x288x2 = 294912
    const size_t oWkb = oWqb + 294912;
    const size_t oWvb = oWkb + 294912;
    const size_t oWfb = oWvb + 294912;             // 256x576x2 = 294912
    const size_t oBbf = oWfb + 294912;             // 131072x288x2 = 75497472
    const size_t oQb  = oBbf + 75497472;           // 32768x512x2 = 33554432
    const size_t oKb  = oQb + 33554432;            // 131072x512x2 (Yv then kb)
    const size_t oVT  = oKb + 134217728;           // 131072x512x2 (Abf first)
    const size_t oSt  = oVT + 134217728;           // 16KB stats
    const size_t FAST_NEED = oSt + 16384;

    if (ws_size >= FAST_NEED) {
        short* Wqb = (short*)(base + oWqb);
        short* Wkb = (short*)(base + oWkb);
        short* Wvb = (short*)(base + oWvb);
        short* Wfb = (short*)(base + oWfb);
        short* Bbf = (short*)(base + oBbf);
        short* qb  = (short*)(base + oQb);
        short* YvKb = (short*)(base + oKb);
        short* vT  = (short*)(base + oVT);
        short* Abf = (short*)(base + oVT);         // alias: dead before vT written
        short* wvb = (short*)(base + oBbf);        // alias: Bbf dead after k-gemm
        short* Yf  = (short*)(base + oQb);         // alias: qb dead after attention
        float* stQ = (float*)(base + oSt);
        float* stK = stQ + 1024;
        float* stV = stQ + 2048;
        float* stF = stQ + 3072;

        hipMemsetAsync(stQ, 0, 16384, stream);

        // bf16 conversions (K padded to 288 / 576)
        cvt_pad<<<32768, 256, 0, stream>>>(A, Abf, 256, 288);
        cvt_pad<<<131072, 256, 0, stream>>>(B, Bbf, 265, 288);
        cvt_pad<<<512, 256, 0, stream>>>(Wq, Wqb, 256, 288);
        cvt_pad<<<512, 256, 0, stream>>>(Wk, Wkb, 265, 288);
        cvt_pad<<<512, 256, 0, stream>>>(Wv, Wvb, 265, 288);
        cvt_pad<<<256, 256, 0, stream>>>(Wf, Wfb, 512, 576);

        // q projection (K=288, padded)
        gemm_bt96<<<dim3(256, 4), 256, 0, stream>>>(
            Abf, Wqb, bq, qb, 512, 288, stQ, a_lens, 7);
        // v projection
        gemm_bt96<<<dim3(1024, 4), 256, 0, stream>>>(
            Bbf, Wvb, bv, YvKb, 512, 288, stV, b_lens, 9);
        finalize_stats<<<1, 512, 0, stream>>>(stV, gv, betav, b_lens, 512);
        apply_v_transpose<<<8192, 256, 0, stream>>>(YvKb, vT, stV);   // kills Abf
        // k projection (overwrites Yv region)
        gemm_bt96<<<dim3(1024, 4), 256, 0, stream>>>(
            Bbf, Wkb, bk, YvKb, 512, 288, stK, b_lens, 9);
        finalize_stats<<<1, 512, 0, stream>>>(stK, gk, betak, b_lens, 512);
        apply_norm512<<<32768, 256, 0, stream>>>(YvKb, stK);
        finalize_stats<<<1, 512, 0, stream>>>(stQ, gq, betaq, a_lens, 512);
        apply_norm512<<<8192, 256, 0, stream>>>(qb, stQ);

        // wv buffer (stride 576, pad cols must be 0) — Bbf dead now
        hipMemsetAsync(wvb, 0, (size_t)32768 * 576 * 2, stream);
        attention<<<dim3(2, 256), 256, 0, stream>>>(qb, YvKb, vT, b_lens, wvb, 576);

        // f projection (K=576, padded)
        gemm_bt96<<<dim3(256, 2), 256, 0, stream>>>(
            wvb, Wfb, bfp, Yf, 256, 576, stF, a_lens, 7);
        finalize_stats<<<1, 512, 0, stream>>>(stF, gf, betaf, a_lens, 256);
        apply_f<<<8192, 256, 0, stream>>>(Yf, stF, a_lens, out);
        return;
    }

    // ---- fallback: R1 layout/path (peak ~335.6 MB, known correct) ----
    short* qb  = (short*)(base);
    short* Yv  = (short*)(base + 33554432);
    short* kb  = Yv;
    short* vT  = (short*)(base + 33554432 + 134217728);
    short* wvb = (short*)(base + 33554432 + 2L * 134217728);
    float* stQ = (float*)(base + 2L * 33554432 + 2L * 134217728);
    float* stK = stQ + 1024;
    float* stV = stQ + 2048;
    float* stF = stQ + 3072;
    short* Yf  = qb;

    hipMemsetAsync(stQ, 0, 16384, stream);

    gemm_bt<false, true><<<dim3(256, 4), 256, 0, stream>>>(
        A, Wq, bq, qb, 512, 256, 256, stQ, a_lens, 7);
    gemm_bt<false, false><<<dim3(1024, 4), 256, 0, stream>>>(
        B, Wv, bv, Yv, 512, 265, 288, stV, b_lens, 9);
    finalize_stats<<<1, 512, 0, stream>>>(stV, gv, betav, b_lens, 512);
    apply_v_transpose<<<8192, 256, 0, stream>>>(Yv, vT, stV);
    gemm_bt<false, false><<<dim3(1024, 4), 256, 0, stream>>>(
        B, Wk, bk, kb, 512, 265, 288, stK, b_lens, 9);
    finalize_stats<<<1, 512, 0, stream>>>(stK, gk, betak, b_lens, 512);
    apply_norm512<<<32768, 256, 0, stream>>>(kb, stK);
    finalize_stats<<<1, 512, 0, stream>>>(stQ, gq, betaq, a_lens, 512);
    apply_norm512<<<8192, 256, 0, stream>>>(qb, stQ);
    attention<<<dim3(2, 256), 256, 0, stream>>>(qb, kb, vT, b_lens, wvb, 512);
    gemm_bt<true, true><<<dim3(256, 2), 256, 0, stream>>>(
        wvb, Wf, bfp, Yf, 256, 512, 512, stF, a_lens, 7);
    finalize_stats<<<1, 512, 0, stream>>>(stF, gf, betaf, a_lens, 256);
    apply_f<<<8192, 256, 0, stream>>>(Yf, stF, a_lens, out);
}

// Round 5
// 890.991 us; speedup vs baseline: 2.0939x; 1.1682x over previous
//
#include <hip/hip_runtime.h>
#include <hip/hip_bf16.h>
#include <stdint.h>

// ---------------------------------------------------------------------------
// AttentionBlock: q/k/v ctx-proj (GEMM + masked-BN + relu + L2norm), attention
// (QK^T -> masked softmax -> PV), f ctx-proj (GEMM + masked-BN + relu), masked.
// Fast path: bf16 operands (K padded), BK=96 GEMM w/ async global_load_lds,
// XCD-swizzled grid (8 blocks sharing an X-tile run on one XCD -> L2 reuse),
// k+v fused in one dispatch, v consumed row-major (LDS transpose in attention).
// Fallback (small ws): R1 path, known correct.
// ---------------------------------------------------------------------------

typedef __attribute__((ext_vector_type(8))) short short8;
typedef __attribute__((ext_vector_type(4))) float floatx4;

__device__ __forceinline__ float bf2f(short h) {
    union { unsigned u; float f; } c;
    c.u = ((unsigned)(unsigned short)h) << 16;
    return c.f;
}
__device__ __forceinline__ short f2bf(float f) {
    union { float f; unsigned u; } c;
    c.f = f;
    unsigned u = c.u + 0x7fffu + ((c.u >> 16) & 1u);  // RNE
    return (short)(u >> 16);
}

__device__ __forceinline__ void async_cp16(const short* g, short* l) {
    __builtin_amdgcn_global_load_lds(
        (const __attribute__((address_space(1))) unsigned int*)g,
        (__attribute__((address_space(3))) unsigned int*)l, 16, 0, 0);
}

__device__ __forceinline__ short8 cvt8load(const float* p) {
    float4 f0 = *(const float4*)(p);
    float4 f1 = *(const float4*)(p + 4);
    short8 r;
    r[0] = f2bf(f0.x); r[1] = f2bf(f0.y); r[2] = f2bf(f0.z); r[3] = f2bf(f0.w);
    r[4] = f2bf(f1.x); r[5] = f2bf(f1.y); r[6] = f2bf(f1.z); r[7] = f2bf(f1.w);
    return r;
}
__device__ __forceinline__ short8 cvt8guard(const float* row, int c0, int Kin) {
    short8 r;
#pragma unroll
    for (int j = 0; j < 8; j++) {
        int c = c0 + j;
        r[j] = (c < Kin) ? f2bf(row[c]) : (short)0;
    }
    return r;
}

// ---------------- convert fp32 -> bf16 with K padding ----------------------
__global__ __launch_bounds__(256) void cvt_pad(const float* __restrict__ in,
                                               short* __restrict__ out,
                                               int kin, int kout) {
    long row = blockIdx.x;
    const float* src = in + row * (long)kin;
    short* dst = out + row * (long)kout;
    for (int c = threadIdx.x; c < kout; c += 256)
        dst[c] = (c < kin) ? f2bf(src[c]) : (short)0;
}

// ---------------- fast BT GEMM: BK=96, XCD-swizzled, optional dual ---------
// Y[m,n] = sum_k X[m,k] W[n,k] + bias[n]; 128x128 tile; Kp % 96 == 0.
// Linear grid; xcd = lin&7. All work items sharing one X-tile (n-blocks x
// optional {0,1} gemm-select) are consecutive slots on one XCD -> L2 reuse.
// Requires (#m-blocks) % 8 == 0. Fused masked BN stats.
__global__ __launch_bounds__(256, 4)
void gemm96s(const short* __restrict__ X,
             const short* __restrict__ W0, const short* __restrict__ W1,
             const float* __restrict__ bias0, const float* __restrict__ bias1,
             short* __restrict__ Y0, short* __restrict__ Y1,
             float* __restrict__ st0, float* __restrict__ st1,
             int N, int Kp, const int* __restrict__ lens, int Lshift,
             int nShift, int dual)
{
    __shared__ short SH[128 * 96 * 2];   // At | Bt ; reused as C-stage 128x132
    short* At = SH;
    short* Bt = SH + 128 * 96;
    const int lin = blockIdx.x;
    const int xcd = lin & 7, sl = lin >> 3;
    const int nb = sl & ((1 << nShift) - 1);
    const int ms = sl >> nShift;
    const int m0 = (ms * 8 + xcd) * 128;
    int g = 0, n0;
    if (dual) { g = nb & 1; n0 = (nb >> 1) * 128; } else { n0 = nb * 128; }
    const short* W    = g ? W1 : W0;
    const float* bias = g ? bias1 : bias0;
    short* Y          = g ? Y1 : Y0;
    float* stats      = g ? st1 : st0;

    const int tid = threadIdx.x;
    const int l = tid & 63, w = tid >> 6;
    const int quad = l >> 4, l15 = l & 15;
    const int mo = (w & 1) * 64, no = (w >> 1) * 64;

    floatx4 acc[4][4];
#pragma unroll
    for (int i = 0; i < 4; i++)
#pragma unroll
        for (int j = 0; j < 4; j++) acc[i][j] = (floatx4){0.f, 0.f, 0.f, 0.f};

    // staging element-offsets (identical for A and B tiles; B = A + delta)
    int offA[6];
#pragma unroll
    for (int c = 0; c < 6; c++) {
        unsigned e = c * 2048u + (unsigned)tid * 8u;   // short index in 128x96 tile
        unsigned row = e / 96u;
        unsigned col = e - row * 96u;
        offA[c] = (int)((unsigned)(m0 + row) * (unsigned)Kp + col);
    }
    const int dB = (n0 - m0) * Kp;

    for (int k0 = 0; k0 < Kp; k0 += 96) {
        __syncthreads();
#pragma unroll
        for (int c = 0; c < 6; c++) {
            async_cp16(X + offA[c] + k0, At + c * 2048 + tid * 8);
            async_cp16(W + offA[c] + dB + k0, Bt + c * 2048 + tid * 8);
        }
        __syncthreads();
#pragma unroll
        for (int seg = 0; seg < 3; seg++) {
            short8 af[4], bfr[4];
#pragma unroll
            for (int i = 0; i < 4; i++) {
                af[i]  = *(const short8*)(At + (mo + i * 16 + l15) * 96 + seg * 32 + quad * 8);
                bfr[i] = *(const short8*)(Bt + (no + i * 16 + l15) * 96 + seg * 32 + quad * 8);
            }
#pragma unroll
            for (int i = 0; i < 4; i++)
#pragma unroll
                for (int j = 0; j < 4; j++)
                    acc[i][j] = __builtin_amdgcn_mfma_f32_16x16x32_bf16(af[i], bfr[j], acc[i][j], 0, 0, 0);
        }
    }

    // ---- epilogue: bias + masked stats + LDS-staged coalesced store ----
    __syncthreads();
    const int Lmask = (1 << Lshift) - 1;
    float msk[4][4];
#pragma unroll
    for (int i = 0; i < 4; i++)
#pragma unroll
        for (int r = 0; r < 4; r++) {
            int rg = m0 + mo + i * 16 + quad * 4 + r;
            msk[i][r] = ((rg & Lmask) < lens[rg >> Lshift]) ? 1.f : 0.f;
        }
    short* Cs = SH;                      // 128 rows, stride 132
#pragma unroll
    for (int j = 0; j < 4; j++) {
        int coll = no + j * 16 + l15;
        float bv = bias[n0 + coll];
        float ps = 0.f, pss = 0.f;
#pragma unroll
        for (int i = 0; i < 4; i++)
#pragma unroll
            for (int r = 0; r < 4; r++) {
                int rl = mo + i * 16 + quad * 4 + r;
                float v = acc[i][j][r] + bv;
                Cs[rl * 132 + coll] = f2bf(v);
                ps += v * msk[i][r];
                pss += v * v * msk[i][r];
            }
        ps  += __shfl_xor(ps, 16, 64);  ps  += __shfl_xor(ps, 32, 64);
        pss += __shfl_xor(pss, 16, 64); pss += __shfl_xor(pss, 32, 64);
        if (l < 16) {
            atomicAdd(&stats[n0 + coll], ps);
            atomicAdd(&stats[N + n0 + coll], pss);
        }
    }
    __syncthreads();
#pragma unroll
    for (int c = 0; c < 8; c++) {
        int e = c * 2048 + tid * 8;
        int row = e >> 7, col = e & 127;
        short8 vv = *(const short8*)(Cs + row * 132 + col);
        *(short8*)(Y + (long)(m0 + row) * N + n0 + col) = vv;
    }
}

// ---------------- fallback BT GEMM (R1: fused fp32 cvt staging) ------------
template<bool XBF16, bool KAL>
__global__ __launch_bounds__(256, 2)
void gemm_bt(const void* __restrict__ Xp, const float* __restrict__ W,
             const float* __restrict__ bias, short* __restrict__ Y,
             int N, int Kin, int Kp, float* __restrict__ stats,
             const int* __restrict__ lens, int Lshift)
{
    __shared__ short At[128 * 32];
    __shared__ short Bt[128 * 32];
    const int m0 = blockIdx.x * 128;
    const int n0 = blockIdx.y * 128;
    const int tid = threadIdx.x;
    const int w = tid >> 6, l = tid & 63;
    const int quad = l >> 4, l15 = l & 15;
    const int mo = (w & 1) * 64, no = (w >> 1) * 64;

    floatx4 acc[4][4];
#pragma unroll
    for (int i = 0; i < 4; i++)
#pragma unroll
        for (int j = 0; j < 4; j++) acc[i][j] = (floatx4){0.f, 0.f, 0.f, 0.f};

    const int srow = tid >> 2;
    const int sc8 = (tid & 3) * 8;

    for (int k0 = 0; k0 < Kp; k0 += 32) {
        __syncthreads();
        const int c0 = k0 + sc8;
        short8 a0, a1, b0, b1;
        if (XBF16) {
            const short* X = (const short*)Xp;
            a0 = *(const short8*)(X + (long)(m0 + srow) * Kp + c0);
            a1 = *(const short8*)(X + (long)(m0 + 64 + srow) * Kp + c0);
        } else {
            const float* X = (const float*)Xp;
            if (KAL) {
                a0 = cvt8load(X + (long)(m0 + srow) * Kin + c0);
                a1 = cvt8load(X + (long)(m0 + 64 + srow) * Kin + c0);
            } else {
                a0 = cvt8guard(X + (long)(m0 + srow) * Kin, c0, Kin);
                a1 = cvt8guard(X + (long)(m0 + 64 + srow) * Kin, c0, Kin);
            }
        }
        if (KAL) {
            b0 = cvt8load(W + (long)(n0 + srow) * Kin + c0);
            b1 = cvt8load(W + (long)(n0 + 64 + srow) * Kin + c0);
        } else {
            b0 = cvt8guard(W + (long)(n0 + srow) * Kin, c0, Kin);
            b1 = cvt8guard(W + (long)(n0 + 64 + srow) * Kin, c0, Kin);
        }
        *(short8*)(At + srow * 32 + sc8) = a0;
        *(short8*)(At + (64 + srow) * 32 + sc8) = a1;
        *(short8*)(Bt + srow * 32 + sc8) = b0;
        *(short8*)(Bt + (64 + srow) * 32 + sc8) = b1;
        __syncthreads();
        short8 af[4], bfr[4];
#pragma unroll
        for (int i = 0; i < 4; i++) {
            af[i]  = *(const short8*)(At + (mo + i * 16 + l15) * 32 + quad * 8);
            bfr[i] = *(const short8*)(Bt + (no + i * 16 + l15) * 32 + quad * 8);
        }
#pragma unroll
        for (int i = 0; i < 4; i++)
#pragma unroll
            for (int j = 0; j < 4; j++)
                acc[i][j] = __builtin_amdgcn_mfma_f32_16x16x32_bf16(af[i], bfr[j], acc[i][j], 0, 0, 0);
    }

    const int Lmask = (1 << Lshift) - 1;
    float msk[4][4];
#pragma unroll
    for (int i = 0; i < 4; i++)
#pragma unroll
        for (int r = 0; r < 4; r++) {
            int rg = m0 + mo + i * 16 + quad * 4 + r;
            msk[i][r] = ((rg & Lmask) < lens[rg >> Lshift]) ? 1.f : 0.f;
        }
#pragma unroll
    for (int j = 0; j < 4; j++) {
        int colj = n0 + no + j * 16 + l15;
        float bv = bias[colj];
        float ps = 0.f, pss = 0.f;
#pragma unroll
        for (int i = 0; i < 4; i++)
#pragma unroll
            for (int r = 0; r < 4; r++) {
                int rg = m0 + mo + i * 16 + quad * 4 + r;
                float v = acc[i][j][r] + bv;
                Y[(long)rg * N + colj] = f2bf(v);
                ps += v * msk[i][r];
                pss += v * v * msk[i][r];
            }
        ps  += __shfl_xor(ps, 16, 64);  ps  += __shfl_xor(ps, 32, 64);
        pss += __shfl_xor(pss, 16, 64); pss += __shfl_xor(pss, 32, 64);
        if (l < 16) {
            atomicAdd(&stats[colj], ps);
            atomicAdd(&stats[N + colj], pss);
        }
    }
}

// ---------------- finalize: stats -> {scale, shift} per channel ------------
__global__ void finalize_stats(float* __restrict__ stats, const float* __restrict__ g,
                               const float* __restrict__ beta,
                               const int* __restrict__ lens, int C)
{
    __shared__ int lred[256];
    int t = threadIdx.x;
    if (t < 256) lred[t] = lens[t];
    __syncthreads();
    for (int s2 = 128; s2 > 0; s2 >>= 1) {
        if (t < s2) lred[t] += lred[t + s2];
        __syncthreads();
    }
    float cnt = (float)lred[0];
    if (t < C) {
        float mean = stats[t] / cnt;
        float var = fmaxf(stats[C + t] / cnt - mean * mean, 0.f);
        float a = rsqrtf(var + 1e-5f) * g[t];
        stats[t] = a;
        stats[C + t] = beta[t] - mean * a;
    }
}

// ---------------- BN + relu + row L2-normalize, C=512, in place ------------
__global__ __launch_bounds__(256)
void apply_norm512(short* __restrict__ Y, const float* __restrict__ stats)
{
    int w = threadIdx.x >> 6, l = threadIdx.x & 63;
    long row = (long)blockIdx.x * 4 + w;
    short8 yv = *(const short8*)(Y + row * 512 + l * 8);
    float v[8];
    float ss = 0.f;
#pragma unroll
    for (int i = 0; i < 8; i++) {
        int c = l * 8 + i;
        float t = fmaxf(bf2f(yv[i]) * stats[c] + stats[512 + c], 0.f);
        v[i] = t;
        ss += t * t;
    }
#pragma unroll
    for (int off = 1; off < 64; off <<= 1) ss += __shfl_xor(ss, off, 64);
    float scl = 1.f / fmaxf(sqrtf(ss), 1e-12f);
    short8 o;
#pragma unroll
    for (int i = 0; i < 8; i++) o[i] = f2bf(v[i] * scl);
    *(short8*)(Y + row * 512 + l * 8) = o;
}

// ---------------- attention: per (s, 64 a-rows) block, XCD-swizzled --------
// v consumed row-major: phase-2 stages a 512b x 32d slice transposed in LDS.
__global__ __launch_bounds__(256)
void attention(const short* __restrict__ q, const short* __restrict__ k,
               const short* __restrict__ v, const int* __restrict__ b_lens,
               short* __restrict__ wv, int wvStride)
{
    __shared__ short tile[32 * 520];
    __shared__ short Pscr[4][16 * 40];
    const int lin = blockIdx.x;
    const int xcd = lin & 7, sl = lin >> 3;       // both a-halves of an s on one XCD
    const int a0 = (sl & 1) * 64;
    const int s = (sl >> 1) * 8 + xcd;
    const int tid = threadIdx.x;
    const int w = tid >> 6, l = tid & 63;
    const int quad = l >> 4, l15 = l & 15;
    const int blen = b_lens[s];
    const int sr = tid >> 3;
    const int scg = (tid & 7) * 8;

    short8 qf[16];
    const short* qbase = q + ((long)(s * 128 + a0 + w * 16 + l15)) * 512 + quad * 8;
#pragma unroll
    for (int kk = 0; kk < 16; kk++) qf[kk] = *(const short8*)(qbase + kk * 32);

    floatx4 sc[32];
#pragma unroll
    for (int i = 0; i < 32; i++) sc[i] = (floatx4){0.f, 0.f, 0.f, 0.f};

    const short* kbase = k + (long)s * 512 * 512;
    for (int bt2 = 0; bt2 < 16; ++bt2) {
        __syncthreads();
        const short* krow = kbase + (long)(bt2 * 32 + sr) * 512;
#pragma unroll
        for (int i = 0; i < 2; i++) {
            short8 t0 = *(const short8*)(krow + i * 256 + scg);
            short8 t1 = *(const short8*)(krow + i * 256 + 64 + scg);
            short8 t2 = *(const short8*)(krow + i * 256 + 128 + scg);
            short8 t3 = *(const short8*)(krow + i * 256 + 192 + scg);
            *(short8*)(&tile[sr * 520 + i * 256 + scg]) = t0;
            *(short8*)(&tile[sr * 520 + i * 256 + 64 + scg]) = t1;
            *(short8*)(&tile[sr * 520 + i * 256 + 128 + scg]) = t2;
            *(short8*)(&tile[sr * 520 + i * 256 + 192 + scg]) = t3;
        }
        __syncthreads();
#pragma unroll
        for (int kk = 0; kk < 16; kk++) {
            short8 f0 = *(const short8*)(&tile[l15 * 520 + kk * 32 + quad * 8]);
            short8 f1 = *(const short8*)(&tile[(16 + l15) * 520 + kk * 32 + quad * 8]);
            sc[bt2 * 2]     = __builtin_amdgcn_mfma_f32_16x16x32_bf16(qf[kk], f0, sc[bt2 * 2], 0, 0, 0);
            sc[bt2 * 2 + 1] = __builtin_amdgcn_mfma_f32_16x16x32_bf16(qf[kk], f1, sc[bt2 * 2 + 1], 0, 0, 0);
        }
    }

    const float scaler = 6.25f;  // 1/(0.01*sqrt(256))
    float mrow[4] = {-__builtin_inff(), -__builtin_inff(), -__builtin_inff(), -__builtin_inff()};
#pragma unroll
    for (int bt = 0; bt < 32; ++bt) {
        bool valid = (bt * 16 + l15) < blen;
#pragma unroll
        for (int r = 0; r < 4; r++) {
            float v2 = valid ? sc[bt][r] * scaler : -__builtin_inff();
            sc[bt][r] = v2;
            mrow[r] = fmaxf(mrow[r], v2);
        }
    }
#pragma unroll
    for (int r = 0; r < 4; r++) {
#pragma unroll
        for (int off = 1; off < 16; off <<= 1)
            mrow[r] = fmaxf(mrow[r], __shfl_xor(mrow[r], off, 64));
    }
    float ssum[4] = {0.f, 0.f, 0.f, 0.f};
#pragma unroll
    for (int bt = 0; bt < 32; ++bt)
#pragma unroll
        for (int r = 0; r < 4; r++) {
            float p = __expf(sc[bt][r] - mrow[r]);
            sc[bt][r] = p;
            ssum[r] += p;
        }
#pragma unroll
    for (int r = 0; r < 4; r++) {
#pragma unroll
        for (int off = 1; off < 16; off <<= 1) ssum[r] += __shfl_xor(ssum[r], off, 64);
        ssum[r] = 1.f / ssum[r];
    }

    short8 pf[16];
    short* Pw = Pscr[w];
#pragma unroll
    for (int kk = 0; kk < 16; kk++) {
#pragma unroll
        for (int half = 0; half < 2; half++)
#pragma unroll
            for (int r = 0; r < 4; r++)
                Pw[(quad * 4 + r) * 40 + half * 16 + l15] = f2bf(sc[kk * 2 + half][r] * ssum[r]);
        pf[kk] = *(const short8*)(&Pw[l15 * 40 + quad * 8]);
    }

    // phase 2: wv[a][d] = sum_b P[a][b] v[b][d]; stage v-slice transposed
    const short* vbase = v + (long)s * 512 * 512;
    short* wvbase = wv + (long)(s * 128 + a0 + w * 16 + quad * 4) * wvStride;
    for (int dt = 0; dt < 16; ++dt) {
        __syncthreads();
#pragma unroll
        for (int round = 0; round < 2; round++) {
            int b = round * 256 + tid;
            const short* vr = vbase + (long)b * 512 + dt * 32;
            short8 x0 = *(const short8*)(vr);
            short8 x1 = *(const short8*)(vr + 8);
            short8 x2 = *(const short8*)(vr + 16);
            short8 x3 = *(const short8*)(vr + 24);
#pragma unroll
            for (int j = 0; j < 8; j++) {
                tile[j * 520 + b]        = x0[j];
                tile[(8 + j) * 520 + b]  = x1[j];
                tile[(16 + j) * 520 + b] = x2[j];
                tile[(24 + j) * 520 + b] = x3[j];
            }
        }
        __syncthreads();
        floatx4 o0 = (floatx4){0.f, 0.f, 0.f, 0.f};
        floatx4 o1 = (floatx4){0.f, 0.f, 0.f, 0.f};
#pragma unroll
        for (int kk = 0; kk < 16; kk++) {
            short8 f0 = *(const short8*)(&tile[l15 * 520 + kk * 32 + quad * 8]);
            short8 f1 = *(const short8*)(&tile[(16 + l15) * 520 + kk * 32 + quad * 8]);
            o0 = __builtin_amdgcn_mfma_f32_16x16x32_bf16(pf[kk], f0, o0, 0, 0, 0);
            o1 = __builtin_amdgcn_mfma_f32_16x16x32_bf16(pf[kk], f1, o1, 0, 0, 0);
        }
#pragma unroll
        for (int r = 0; r < 4; r++) {
            wvbase[(long)r * wvStride + dt * 32 + l15]      = f2bf(o0[r]);
            wvbase[(long)r * wvStride + dt * 32 + 16 + l15] = f2bf(o1[r]);
        }
    }

    // zero wv pad columns (K-pad for the f-gemm) — replaces a 37MB memset
    if (wvStride > 512) {
        int r = tid >> 2, cb = (tid & 3) * 16;
        short8 z = (short8){0, 0, 0, 0, 0, 0, 0, 0};
        short* pz = wv + (long)(s * 128 + a0 + r) * wvStride + 512 + cb;
        *(short8*)(pz) = z;
        *(short8*)(pz + 8) = z;
    }
}

// ---------------- f: BN + relu + mask_a -> d_out fp32 ----------------------
__global__ __launch_bounds__(256)
void apply_f(const short* __restrict__ Yf, const float* __restrict__ stats,
             const int* __restrict__ a_lens, float* __restrict__ out)
{
    const long total = (long)32768 * 256;
    for (long e = (long)blockIdx.x * 256 + threadIdx.x; e < total; e += (long)gridDim.x * 256) {
        int c = (int)(e & 255);
        long row = e >> 8;
        int sI = (int)(row >> 7), pos = (int)(row & 127);
        float v = fmaxf(bf2f(Yf[e]) * stats[c] + stats[256 + c], 0.f);
        out[e] = (pos < a_lens[sI]) ? v : 0.f;
    }
}

// ---------------------------------------------------------------------------
extern "C" void kernel_launch(void* const* d_in, const int* in_sizes, int n_in,
                              void* d_out, int out_size, void* d_ws, size_t ws_size,
                              hipStream_t stream)
{
    (void)in_sizes; (void)n_in; (void)out_size;
    const float* A     = (const float*)d_in[0];
    const float* B     = (const float*)d_in[1];
    const int* a_lens  = (const int*)d_in[2];
    const int* b_lens  = (const int*)d_in[3];
    const float* Wq    = (const float*)d_in[4];
    const float* bq    = (const float*)d_in[5];
    const float* gq    = (const float*)d_in[6];
    const float* betaq = (const float*)d_in[7];
    const float* Wk    = (const float*)d_in[8];
    const float* bk    = (const float*)d_in[9];
    const float* gk    = (const float*)d_in[10];
    const float* betak = (const float*)d_in[11];
    const float* Wv    = (const float*)d_in[12];
    const float* bv    = (const float*)d_in[13];
    const float* gv    = (const float*)d_in[14];
    const float* betav = (const float*)d_in[15];
    const float* Wf    = (const float*)d_in[16];
    const float* bfp   = (const float*)d_in[17];
    const float* gf    = (const float*)d_in[18];
    const float* betaf = (const float*)d_in[19];
    float* out = (float*)d_out;
    char* base = (char*)d_ws;

    // ---- fast layout (378.7 MB; same FAST_NEED as R3/R4, proven OK) ----
    const size_t oWqb = 0;                         // 512x288x2
    const size_t oWkb = oWqb + 294912;
    const size_t oWvb = oWkb + 294912;
    const size_t oWfb = oWvb + 294912;             // 256x576x2
    const size_t oBbf = oWfb + 294912;             // 131072x288x2 = 75497472
    const size_t oQb  = oBbf + 75497472;           // 32768x512x2
    const size_t oYv  = oQb + 33554432;            // 131072x512x2 (v rows)
    const size_t oKb  = oYv + 134217728;           // 131072x512x2 (Abf first)
    const size_t oSt  = oKb + 134217728;           // 16KB stats
    const size_t FAST_NEED = oSt + 16384;

    if (ws_size >= FAST_NEED) {
        short* Wqb = (short*)(base + oWqb);
        short* Wkb = (short*)(base + oWkb);
        short* Wvb = (short*)(base + oWvb);
        short* Wfb = (short*)(base + oWfb);
        short* Bbf = (short*)(base + oBbf);
        short* qb  = (short*)(base + oQb);
        short* Yv  = (short*)(base + oYv);
        short* kb  = (short*)(base + oKb);
        short* Abf = (short*)(base + oKb);         // alias: dead before kb written
        short* wvb = (short*)(base + oBbf);        // alias: Bbf dead after kv-gemm
        short* Yf  = (short*)(base + oQb);         // alias: qb dead after attention
        float* stQ = (float*)(base + oSt);
        float* stK = stQ + 1024;
        float* stV = stQ + 2048;
        float* stF = stQ + 3072;

        hipMemsetAsync(stQ, 0, 16384, stream);

        // bf16 conversions (K padded to 288 / 576)
        cvt_pad<<<32768, 256, 0, stream>>>(A, Abf, 256, 288);
        cvt_pad<<<131072, 256, 0, stream>>>(B, Bbf, 265, 288);
        cvt_pad<<<512, 256, 0, stream>>>(Wq, Wqb, 256, 288);
        cvt_pad<<<512, 256, 0, stream>>>(Wk, Wkb, 265, 288);
        cvt_pad<<<512, 256, 0, stream>>>(Wv, Wvb, 265, 288);
        cvt_pad<<<256, 256, 0, stream>>>(Wf, Wfb, 512, 576);

        // q projection: 256 m-blocks x 4 n-blocks, swizzled
        gemm96s<<<1024, 256, 0, stream>>>(
            Abf, Wqb, Wqb, bq, bq, qb, qb, stQ, stQ, 512, 288, a_lens, 7, 2, 0);
        // fused k+v: 1024 m-blocks x 4 n x {v,k}, swizzled (clobbers Abf)
        gemm96s<<<8192, 256, 0, stream>>>(
            Bbf, Wvb, Wkb, bv, bk, Yv, kb, stV, stK, 512, 288, b_lens, 9, 3, 1);

        finalize_stats<<<1, 512, 0, stream>>>(stV, gv, betav, b_lens, 512);
        finalize_stats<<<1, 512, 0, stream>>>(stK, gk, betak, b_lens, 512);
        finalize_stats<<<1, 512, 0, stream>>>(stQ, gq, betaq, a_lens, 512);
        apply_norm512<<<32768, 256, 0, stream>>>(Yv, stV);
        apply_norm512<<<32768, 256, 0, stream>>>(kb, stK);
        apply_norm512<<<8192, 256, 0, stream>>>(qb, stQ);

        // attention (v row-major; writes wv incl. zeroed pad cols)
        attention<<<512, 256, 0, stream>>>(qb, kb, Yv, b_lens, wvb, 576);

        // f projection: 256 m-blocks x 2 n-blocks, swizzled (K=576)
        gemm96s<<<512, 256, 0, stream>>>(
            wvb, Wfb, Wfb, bfp, bfp, Yf, Yf, stF, stF, 256, 576, a_lens, 7, 1, 0);
        finalize_stats<<<1, 512, 0, stream>>>(stF, gf, betaf, a_lens, 256);
        apply_f<<<8192, 256, 0, stream>>>(Yf, stF, a_lens, out);
        return;
    }

    // ---- fallback: R1-style path (peak ~335.6 MB, known correct) ----
    short* qb  = (short*)(base);
    short* Yv  = (short*)(base + 33554432);
    short* kb  = (short*)(base + 33554432 + 134217728);
    short* wvb = (short*)(base + 33554432 + 2L * 134217728);
    float* stQ = (float*)(base + 2L * 33554432 + 2L * 134217728);
    float* stK = stQ + 1024;
    float* stV = stQ + 2048;
    float* stF = stQ + 3072;
    short* Yf  = qb;

    hipMemsetAsync(stQ, 0, 16384, stream);

    gemm_bt<false, true><<<dim3(256, 4), 256, 0, stream>>>(
        A, Wq, bq, qb, 512, 256, 256, stQ, a_lens, 7);
    gemm_bt<false, false><<<dim3(1024, 4), 256, 0, stream>>>(
        B, Wv, bv, Yv, 512, 265, 288, stV, b_lens, 9);
    finalize_stats<<<1, 512, 0, stream>>>(stV, gv, betav, b_lens, 512);
    apply_norm512<<<32768, 256, 0, stream>>>(Yv, stV);
    gemm_bt<false, false><<<dim3(1024, 4), 256, 0, stream>>>(
        B, Wk, bk, kb, 512, 265, 288, stK, b_lens, 9);
    finalize_stats<<<1, 512, 0, stream>>>(stK, gk, betak, b_lens, 512);
    apply_norm512<<<32768, 256, 0, stream>>>(kb, stK);
    finalize_stats<<<1, 512, 0, stream>>>(stQ, gq, betaq, a_lens, 512);
    apply_norm512<<<8192, 256, 0, stream>>>(qb, stQ);
    attention<<<512, 256, 0, stream>>>(qb, kb, Yv, b_lens, wvb, 512);
    gemm_bt<true, true><<<dim3(256, 2), 256, 0, stream>>>(
        wvb, Wf, bfp, Yf, 256, 512, 512, stF, a_lens, 7);
    finalize_stats<<<1, 512, 0, stream>>>(stF, gf, betaf, a_lens, 256);
    apply_f<<<8192, 256, 0, stream>>>(Yf, stF, a_lens, out);
}

// Round 6
// 857.769 us; speedup vs baseline: 2.1750x; 1.0387x over previous
//
#include <hip/hip_runtime.h>
#include <hip/hip_bf16.h>
#include <stdint.h>

// ---------------------------------------------------------------------------
// AttentionBlock: q/k/v ctx-proj (GEMM + masked-BN + relu + L2norm), attention
// (QK^T -> masked softmax -> PV), f ctx-proj (GEMM + masked-BN + relu), masked.
// Fast path: bf16 operands (K padded), 256x128-tile BK=96 GEMM w/ async
// global_load_lds, XCD-swizzled grid (L2 reuse), k+v fused in one dispatch,
// v consumed row-major (LDS transpose in attention).
// Fallback (small ws): R1 path, known correct.
// ---------------------------------------------------------------------------

typedef __attribute__((ext_vector_type(8))) short short8;
typedef __attribute__((ext_vector_type(4))) float floatx4;

__device__ __forceinline__ float bf2f(short h) {
    union { unsigned u; float f; } c;
    c.u = ((unsigned)(unsigned short)h) << 16;
    return c.f;
}
__device__ __forceinline__ short f2bf(float f) {
    union { float f; unsigned u; } c;
    c.f = f;
    unsigned u = c.u + 0x7fffu + ((c.u >> 16) & 1u);  // RNE
    return (short)(u >> 16);
}

__device__ __forceinline__ void async_cp16(const short* g, short* l) {
    __builtin_amdgcn_global_load_lds(
        (const __attribute__((address_space(1))) unsigned int*)g,
        (__attribute__((address_space(3))) unsigned int*)l, 16, 0, 0);
}

__device__ __forceinline__ short8 cvt8load(const float* p) {
    float4 f0 = *(const float4*)(p);
    float4 f1 = *(const float4*)(p + 4);
    short8 r;
    r[0] = f2bf(f0.x); r[1] = f2bf(f0.y); r[2] = f2bf(f0.z); r[3] = f2bf(f0.w);
    r[4] = f2bf(f1.x); r[5] = f2bf(f1.y); r[6] = f2bf(f1.z); r[7] = f2bf(f1.w);
    return r;
}
__device__ __forceinline__ short8 cvt8guard(const float* row, int c0, int Kin) {
    short8 r;
#pragma unroll
    for (int j = 0; j < 8; j++) {
        int c = c0 + j;
        r[j] = (c < Kin) ? f2bf(row[c]) : (short)0;
    }
    return r;
}

// ---------------- convert fp32 -> bf16 with K padding ----------------------
__global__ __launch_bounds__(256) void cvt_pad(const float* __restrict__ in,
                                               short* __restrict__ out,
                                               int kin, int kout) {
    long row = blockIdx.x;
    const float* src = in + row * (long)kin;
    short* dst = out + row * (long)kout;
    for (int c = threadIdx.x; c < kout; c += 256)
        dst[c] = (c < kin) ? f2bf(src[c]) : (short)0;
}

// ---------------- fast BT GEMM: 256x128 tile, BK=96, XCD-swizzled ----------
// Y[m,n] = sum_k X[m,k] W[n,k] + bias[n]; Kp % 96 == 0; M % 2048 == 0.
// Linear grid; xcd = lin&7; work items sharing an X-tile are consecutive on
// one XCD -> L2 reuse. Per wave: 64 rows x 128 cols (acc 4x8). Fused masked
// BN stats; LDS-staged coalesced C store.
__global__ __launch_bounds__(256, 2)
void gemm256(const short* __restrict__ X,
             const short* __restrict__ W0, const short* __restrict__ W1,
             const float* __restrict__ bias0, const float* __restrict__ bias1,
             short* __restrict__ Y0, short* __restrict__ Y1,
             float* __restrict__ st0, float* __restrict__ st1,
             int N, int Kp, const int* __restrict__ lens, int Lshift,
             int nShift, int dual)
{
    __shared__ short SH[(256 + 128) * 96];   // At(256x96) | Bt(128x96); C-stage 256x132
    short* At = SH;
    short* Bt = SH + 256 * 96;
    const int lin = blockIdx.x;
    const int xcd = lin & 7, sl = lin >> 3;
    const int nb = sl & ((1 << nShift) - 1);
    const int ms = sl >> nShift;
    const int m0 = (ms * 8 + xcd) * 256;
    int g = 0, n0;
    if (dual) { g = nb & 1; n0 = (nb >> 1) * 128; } else { n0 = nb * 128; }
    const short* W    = g ? W1 : W0;
    const float* bias = g ? bias1 : bias0;
    short* Y          = g ? Y1 : Y0;
    float* stats      = g ? st1 : st0;

    const int tid = threadIdx.x;
    const int l = tid & 63, w = tid >> 6;
    const int quad = l >> 4, l15 = l & 15;
    const int mo = w * 64;                   // wave's 64-row slice

    floatx4 acc[4][8];
#pragma unroll
    for (int i = 0; i < 4; i++)
#pragma unroll
        for (int j = 0; j < 8; j++) acc[i][j] = (floatx4){0.f, 0.f, 0.f, 0.f};

    // staging element-offsets
    int offA[12], offB[6];
#pragma unroll
    for (int c = 0; c < 12; c++) {
        unsigned e = c * 2048u + (unsigned)tid * 8u;   // short idx in 256x96 tile
        unsigned row = e / 96u;
        unsigned col = e - row * 96u;
        offA[c] = (int)((unsigned)(m0 + row) * (unsigned)Kp + col);
    }
#pragma unroll
    for (int c = 0; c < 6; c++) {
        unsigned e = c * 2048u + (unsigned)tid * 8u;   // short idx in 128x96 tile
        unsigned row = e / 96u;
        unsigned col = e - row * 96u;
        offB[c] = (int)((unsigned)(n0 + row) * (unsigned)Kp + col);
    }

    for (int k0 = 0; k0 < Kp; k0 += 96) {
        __syncthreads();
#pragma unroll
        for (int c = 0; c < 12; c++)
            async_cp16(X + offA[c] + k0, At + c * 2048 + tid * 8);
#pragma unroll
        for (int c = 0; c < 6; c++)
            async_cp16(W + offB[c] + k0, Bt + c * 2048 + tid * 8);
        __syncthreads();
#pragma unroll
        for (int seg = 0; seg < 3; seg++) {
            short8 af[4], bfr[8];
#pragma unroll
            for (int i = 0; i < 4; i++)
                af[i] = *(const short8*)(At + (mo + i * 16 + l15) * 96 + seg * 32 + quad * 8);
#pragma unroll
            for (int j = 0; j < 8; j++)
                bfr[j] = *(const short8*)(Bt + (j * 16 + l15) * 96 + seg * 32 + quad * 8);
#pragma unroll
            for (int i = 0; i < 4; i++)
#pragma unroll
                for (int j = 0; j < 8; j++)
                    acc[i][j] = __builtin_amdgcn_mfma_f32_16x16x32_bf16(af[i], bfr[j], acc[i][j], 0, 0, 0);
        }
    }

    // ---- epilogue: bias + masked stats + LDS-staged coalesced store ----
    __syncthreads();
    const int Lmask = (1 << Lshift) - 1;
    float msk[4][4];
#pragma unroll
    for (int i = 0; i < 4; i++)
#pragma unroll
        for (int r = 0; r < 4; r++) {
            int rg = m0 + mo + i * 16 + quad * 4 + r;
            msk[i][r] = ((rg & Lmask) < lens[rg >> Lshift]) ? 1.f : 0.f;
        }
    short* Cs = SH;                          // 256 rows, stride 132 (67.6KB)
#pragma unroll
    for (int j = 0; j < 8; j++) {
        int coll = j * 16 + l15;
        float bv = bias[n0 + coll];
        float ps = 0.f, pss = 0.f;
#pragma unroll
        for (int i = 0; i < 4; i++)
#pragma unroll
            for (int r = 0; r < 4; r++) {
                int rl = mo + i * 16 + quad * 4 + r;
                float v = acc[i][j][r] + bv;
                Cs[rl * 132 + coll] = f2bf(v);
                ps += v * msk[i][r];
                pss += v * v * msk[i][r];
            }
        ps  += __shfl_xor(ps, 16, 64);  ps  += __shfl_xor(ps, 32, 64);
        pss += __shfl_xor(pss, 16, 64); pss += __shfl_xor(pss, 32, 64);
        if (l < 16) {
            atomicAdd(&stats[n0 + coll], ps);
            atomicAdd(&stats[N + n0 + coll], pss);
        }
    }
    __syncthreads();
#pragma unroll
    for (int c = 0; c < 16; c++) {
        int e = c * 2048 + tid * 8;          // 256*128 tile, row-major
        int row = e >> 7, col = e & 127;
        short8 vv = *(const short8*)(Cs + row * 132 + col);
        *(short8*)(Y + (long)(m0 + row) * N + n0 + col) = vv;
    }
}

// ---------------- fallback BT GEMM (R1: fused fp32 cvt staging) ------------
template<bool XBF16, bool KAL>
__global__ __launch_bounds__(256, 2)
void gemm_bt(const void* __restrict__ Xp, const float* __restrict__ W,
             const float* __restrict__ bias, short* __restrict__ Y,
             int N, int Kin, int Kp, float* __restrict__ stats,
             const int* __restrict__ lens, int Lshift)
{
    __shared__ short At[128 * 32];
    __shared__ short Bt[128 * 32];
    const int m0 = blockIdx.x * 128;
    const int n0 = blockIdx.y * 128;
    const int tid = threadIdx.x;
    const int w = tid >> 6, l = tid & 63;
    const int quad = l >> 4, l15 = l & 15;
    const int mo = (w & 1) * 64, no = (w >> 1) * 64;

    floatx4 acc[4][4];
#pragma unroll
    for (int i = 0; i < 4; i++)
#pragma unroll
        for (int j = 0; j < 4; j++) acc[i][j] = (floatx4){0.f, 0.f, 0.f, 0.f};

    const int srow = tid >> 2;
    const int sc8 = (tid & 3) * 8;

    for (int k0 = 0; k0 < Kp; k0 += 32) {
        __syncthreads();
        const int c0 = k0 + sc8;
        short8 a0, a1, b0, b1;
        if (XBF16) {
            const short* X = (const short*)Xp;
            a0 = *(const short8*)(X + (long)(m0 + srow) * Kp + c0);
            a1 = *(const short8*)(X + (long)(m0 + 64 + srow) * Kp + c0);
        } else {
            const float* X = (const float*)Xp;
            if (KAL) {
                a0 = cvt8load(X + (long)(m0 + srow) * Kin + c0);
                a1 = cvt8load(X + (long)(m0 + 64 + srow) * Kin + c0);
            } else {
                a0 = cvt8guard(X + (long)(m0 + srow) * Kin, c0, Kin);
                a1 = cvt8guard(X + (long)(m0 + 64 + srow) * Kin, c0, Kin);
            }
        }
        if (KAL) {
            b0 = cvt8load(W + (long)(n0 + srow) * Kin + c0);
            b1 = cvt8load(W + (long)(n0 + 64 + srow) * Kin + c0);
        } else {
            b0 = cvt8guard(W + (long)(n0 + srow) * Kin, c0, Kin);
            b1 = cvt8guard(W + (long)(n0 + 64 + srow) * Kin, c0, Kin);
        }
        *(short8*)(At + srow * 32 + sc8) = a0;
        *(short8*)(At + (64 + srow) * 32 + sc8) = a1;
        *(short8*)(Bt + srow * 32 + sc8) = b0;
        *(short8*)(Bt + (64 + srow) * 32 + sc8) = b1;
        __syncthreads();
        short8 af[4], bfr[4];
#pragma unroll
        for (int i = 0; i < 4; i++) {
            af[i]  = *(const short8*)(At + (mo + i * 16 + l15) * 32 + quad * 8);
            bfr[i] = *(const short8*)(Bt + (no + i * 16 + l15) * 32 + quad * 8);
        }
#pragma unroll
        for (int i = 0; i < 4; i++)
#pragma unroll
            for (int j = 0; j < 4; j++)
                acc[i][j] = __builtin_amdgcn_mfma_f32_16x16x32_bf16(af[i], bfr[j], acc[i][j], 0, 0, 0);
    }

    const int Lmask = (1 << Lshift) - 1;
    float msk[4][4];
#pragma unroll
    for (int i = 0; i < 4; i++)
#pragma unroll
        for (int r = 0; r < 4; r++) {
            int rg = m0 + mo + i * 16 + quad * 4 + r;
            msk[i][r] = ((rg & Lmask) < lens[rg >> Lshift]) ? 1.f : 0.f;
        }
#pragma unroll
    for (int j = 0; j < 4; j++) {
        int colj = n0 + no + j * 16 + l15;
        float bv = bias[colj];
        float ps = 0.f, pss = 0.f;
#pragma unroll
        for (int i = 0; i < 4; i++)
#pragma unroll
            for (int r = 0; r < 4; r++) {
                int rg = m0 + mo + i * 16 + quad * 4 + r;
                float v = acc[i][j][r] + bv;
                Y[(long)rg * N + colj] = f2bf(v);
                ps += v * msk[i][r];
                pss += v * v * msk[i][r];
            }
        ps  += __shfl_xor(ps, 16, 64);  ps  += __shfl_xor(ps, 32, 64);
        pss += __shfl_xor(pss, 16, 64); pss += __shfl_xor(pss, 32, 64);
        if (l < 16) {
            atomicAdd(&stats[colj], ps);
            atomicAdd(&stats[N + colj], pss);
        }
    }
}

// ---------------- finalize: stats -> {scale, shift} per channel ------------
__global__ void finalize_stats(float* __restrict__ stats, const float* __restrict__ g,
                               const float* __restrict__ beta,
                               const int* __restrict__ lens, int C)
{
    __shared__ int lred[256];
    int t = threadIdx.x;
    if (t < 256) lred[t] = lens[t];
    __syncthreads();
    for (int s2 = 128; s2 > 0; s2 >>= 1) {
        if (t < s2) lred[t] += lred[t + s2];
        __syncthreads();
    }
    float cnt = (float)lred[0];
    if (t < C) {
        float mean = stats[t] / cnt;
        float var = fmaxf(stats[C + t] / cnt - mean * mean, 0.f);
        float a = rsqrtf(var + 1e-5f) * g[t];
        stats[t] = a;
        stats[C + t] = beta[t] - mean * a;
    }
}

// ---------------- BN + relu + row L2-normalize, C=512, in place ------------
__global__ __launch_bounds__(256)
void apply_norm512(short* __restrict__ Y, const float* __restrict__ stats)
{
    int w = threadIdx.x >> 6, l = threadIdx.x & 63;
    long row = (long)blockIdx.x * 4 + w;
    short8 yv = *(const short8*)(Y + row * 512 + l * 8);
    float v[8];
    float ss = 0.f;
#pragma unroll
    for (int i = 0; i < 8; i++) {
        int c = l * 8 + i;
        float t = fmaxf(bf2f(yv[i]) * stats[c] + stats[512 + c], 0.f);
        v[i] = t;
        ss += t * t;
    }
#pragma unroll
    for (int off = 1; off < 64; off <<= 1) ss += __shfl_xor(ss, off, 64);
    float scl = 1.f / fmaxf(sqrtf(ss), 1e-12f);
    short8 o;
#pragma unroll
    for (int i = 0; i < 8; i++) o[i] = f2bf(v[i] * scl);
    *(short8*)(Y + row * 512 + l * 8) = o;
}

// ---------------- attention: per (s, 64 a-rows) block, XCD-swizzled --------
// v consumed row-major: phase-2 stages a 512b x 32d slice transposed in LDS.
__global__ __launch_bounds__(256)
void attention(const short* __restrict__ q, const short* __restrict__ k,
               const short* __restrict__ v, const int* __restrict__ b_lens,
               short* __restrict__ wv, int wvStride)
{
    __shared__ short tile[32 * 520];
    __shared__ short Pscr[4][16 * 40];
    const int lin = blockIdx.x;
    const int xcd = lin & 7, sl = lin >> 3;       // both a-halves of an s on one XCD
    const int a0 = (sl & 1) * 64;
    const int s = (sl >> 1) * 8 + xcd;
    const int tid = threadIdx.x;
    const int w = tid >> 6, l = tid & 63;
    const int quad = l >> 4, l15 = l & 15;
    const int blen = b_lens[s];
    const int sr = tid >> 3;
    const int scg = (tid & 7) * 8;

    short8 qf[16];
    const short* qbase = q + ((long)(s * 128 + a0 + w * 16 + l15)) * 512 + quad * 8;
#pragma unroll
    for (int kk = 0; kk < 16; kk++) qf[kk] = *(const short8*)(qbase + kk * 32);

    floatx4 sc[32];
#pragma unroll
    for (int i = 0; i < 32; i++) sc[i] = (floatx4){0.f, 0.f, 0.f, 0.f};

    const short* kbase = k + (long)s * 512 * 512;
    for (int bt2 = 0; bt2 < 16; ++bt2) {
        __syncthreads();
        const short* krow = kbase + (long)(bt2 * 32 + sr) * 512;
#pragma unroll
        for (int i = 0; i < 2; i++) {
            short8 t0 = *(const short8*)(krow + i * 256 + scg);
            short8 t1 = *(const short8*)(krow + i * 256 + 64 + scg);
            short8 t2 = *(const short8*)(krow + i * 256 + 128 + scg);
            short8 t3 = *(const short8*)(krow + i * 256 + 192 + scg);
            *(short8*)(&tile[sr * 520 + i * 256 + scg]) = t0;
            *(short8*)(&tile[sr * 520 + i * 256 + 64 + scg]) = t1;
            *(short8*)(&tile[sr * 520 + i * 256 + 128 + scg]) = t2;
            *(short8*)(&tile[sr * 520 + i * 256 + 192 + scg]) = t3;
        }
        __syncthreads();
#pragma unroll
        for (int kk = 0; kk < 16; kk++) {
            short8 f0 = *(const short8*)(&tile[l15 * 520 + kk * 32 + quad * 8]);
            short8 f1 = *(const short8*)(&tile[(16 + l15) * 520 + kk * 32 + quad * 8]);
            sc[bt2 * 2]     = __builtin_amdgcn_mfma_f32_16x16x32_bf16(qf[kk], f0, sc[bt2 * 2], 0, 0, 0);
            sc[bt2 * 2 + 1] = __builtin_amdgcn_mfma_f32_16x16x32_bf16(qf[kk], f1, sc[bt2 * 2 + 1], 0, 0, 0);
        }
    }

    const float scaler = 6.25f;  // 1/(0.01*sqrt(256))
    float mrow[4] = {-__builtin_inff(), -__builtin_inff(), -__builtin_inff(), -__builtin_inff()};
#pragma unroll
    for (int bt = 0; bt < 32; ++bt) {
        bool valid = (bt * 16 + l15) < blen;
#pragma unroll
        for (int r = 0; r < 4; r++) {
            float v2 = valid ? sc[bt][r] * scaler : -__builtin_inff();
            sc[bt][r] = v2;
            mrow[r] = fmaxf(mrow[r], v2);
        }
    }
#pragma unroll
    for (int r = 0; r < 4; r++) {
#pragma unroll
        for (int off = 1; off < 16; off <<= 1)
            mrow[r] = fmaxf(mrow[r], __shfl_xor(mrow[r], off, 64));
    }
    float ssum[4] = {0.f, 0.f, 0.f, 0.f};
#pragma unroll
    for (int bt = 0; bt < 32; ++bt)
#pragma unroll
        for (int r = 0; r < 4; r++) {
            float p = __expf(sc[bt][r] - mrow[r]);
            sc[bt][r] = p;
            ssum[r] += p;
        }
#pragma unroll
    for (int r = 0; r < 4; r++) {
#pragma unroll
        for (int off = 1; off < 16; off <<= 1) ssum[r] += __shfl_xor(ssum[r], off, 64);
        ssum[r] = 1.f / ssum[r];
    }

    short8 pf[16];
    short* Pw = Pscr[w];
#pragma unroll
    for (int kk = 0; kk < 16; kk++) {
#pragma unroll
        for (int half = 0; half < 2; half++)
#pragma unroll
            for (int r = 0; r < 4; r++)
                Pw[(quad * 4 + r) * 40 + half * 16 + l15] = f2bf(sc[kk * 2 + half][r] * ssum[r]);
        pf[kk] = *(const short8*)(&Pw[l15 * 40 + quad * 8]);
    }

    // phase 2: wv[a][d] = sum_b P[a][b] v[b][d]; stage v-slice transposed
    const short* vbase = v + (long)s * 512 * 512;
    short* wvbase = wv + (long)(s * 128 + a0 + w * 16 + quad * 4) * wvStride;
    for (int dt = 0; dt < 16; ++dt) {
        __syncthreads();
#pragma unroll
        for (int round = 0; round < 2; round++) {
            int b = round * 256 + tid;
            const short* vr = vbase + (long)b * 512 + dt * 32;
            short8 x0 = *(const short8*)(vr);
            short8 x1 = *(const short8*)(vr + 8);
            short8 x2 = *(const short8*)(vr + 16);
            short8 x3 = *(const short8*)(vr + 24);
#pragma unroll
            for (int j = 0; j < 8; j++) {
                tile[j * 520 + b]        = x0[j];
                tile[(8 + j) * 520 + b]  = x1[j];
                tile[(16 + j) * 520 + b] = x2[j];
                tile[(24 + j) * 520 + b] = x3[j];
            }
        }
        __syncthreads();
        floatx4 o0 = (floatx4){0.f, 0.f, 0.f, 0.f};
        floatx4 o1 = (floatx4){0.f, 0.f, 0.f, 0.f};
#pragma unroll
        for (int kk = 0; kk < 16; kk++) {
            short8 f0 = *(const short8*)(&tile[l15 * 520 + kk * 32 + quad * 8]);
            short8 f1 = *(const short8*)(&tile[(16 + l15) * 520 + kk * 32 + quad * 8]);
            o0 = __builtin_amdgcn_mfma_f32_16x16x32_bf16(pf[kk], f0, o0, 0, 0, 0);
            o1 = __builtin_amdgcn_mfma_f32_16x16x32_bf16(pf[kk], f1, o1, 0, 0, 0);
        }
#pragma unroll
        for (int r = 0; r < 4; r++) {
            wvbase[(long)r * wvStride + dt * 32 + l15]      = f2bf(o0[r]);
            wvbase[(long)r * wvStride + dt * 32 + 16 + l15] = f2bf(o1[r]);
        }
    }

    // zero wv pad columns (K-pad for the f-gemm)
    if (wvStride > 512) {
        int r = tid >> 2, cb = (tid & 3) * 16;
        short8 z = (short8){0, 0, 0, 0, 0, 0, 0, 0};
        short* pz = wv + (long)(s * 128 + a0 + r) * wvStride + 512 + cb;
        *(short8*)(pz) = z;
        *(short8*)(pz + 8) = z;
    }
}

// ---------------- f: BN + relu + mask_a -> d_out fp32 ----------------------
__global__ __launch_bounds__(256)
void apply_f(const short* __restrict__ Yf, const float* __restrict__ stats,
             const int* __restrict__ a_lens, float* __restrict__ out)
{
    const long total = (long)32768 * 256;
    for (long e = (long)blockIdx.x * 256 + threadIdx.x; e < total; e += (long)gridDim.x * 256) {
        int c = (int)(e & 255);
        long row = e >> 8;
        int sI = (int)(row >> 7), pos = (int)(row & 127);
        float v = fmaxf(bf2f(Yf[e]) * stats[c] + stats[256 + c], 0.f);
        out[e] = (pos < a_lens[sI]) ? v : 0.f;
    }
}

// ---------------------------------------------------------------------------
extern "C" void kernel_launch(void* const* d_in, const int* in_sizes, int n_in,
                              void* d_out, int out_size, void* d_ws, size_t ws_size,
                              hipStream_t stream)
{
    (void)in_sizes; (void)n_in; (void)out_size;
    const float* A     = (const float*)d_in[0];
    const float* B     = (const float*)d_in[1];
    const int* a_lens  = (const int*)d_in[2];
    const int* b_lens  = (const int*)d_in[3];
    const float* Wq    = (const float*)d_in[4];
    const float* bq    = (const float*)d_in[5];
    const float* gq    = (const float*)d_in[6];
    const float* betaq = (const float*)d_in[7];
    const float* Wk    = (const float*)d_in[8];
    const float* bk    = (const float*)d_in[9];
    const float* gk    = (const float*)d_in[10];
    const float* betak = (const float*)d_in[11];
    const float* Wv    = (const float*)d_in[12];
    const float* bv    = (const float*)d_in[13];
    const float* gv    = (const float*)d_in[14];
    const float* betav = (const float*)d_in[15];
    const float* Wf    = (const float*)d_in[16];
    const float* bfp   = (const float*)d_in[17];
    const float* gf    = (const float*)d_in[18];
    const float* betaf = (const float*)d_in[19];
    float* out = (float*)d_out;
    char* base = (char*)d_ws;

    // ---- fast layout (378.7 MB; same FAST_NEED as R3-R5, proven OK) ----
    const size_t oWqb = 0;                         // 512x288x2
    const size_t oWkb = oWqb + 294912;
    const size_t oWvb = oWkb + 294912;
    const size_t oWfb = oWvb + 294912;             // 256x576x2
    const size_t oBbf = oWfb + 294912;             // 131072x288x2 = 75497472
    const size_t oQb  = oBbf + 75497472;           // 32768x512x2
    const size_t oYv  = oQb + 33554432;            // 131072x512x2 (v rows)
    const size_t oKb  = oYv + 134217728;           // 131072x512x2 (Abf first)
    const size_t oSt  = oKb + 134217728;           // 16KB stats
    const size_t FAST_NEED = oSt + 16384;

    if (ws_size >= FAST_NEED) {
        short* Wqb = (short*)(base + oWqb);
        short* Wkb = (short*)(base + oWkb);
        short* Wvb = (short*)(base + oWvb);
        short* Wfb = (short*)(base + oWfb);
        short* Bbf = (short*)(base + oBbf);
        short* qb  = (short*)(base + oQb);
        short* Yv  = (short*)(base + oYv);
        short* kb  = (short*)(base + oKb);
        short* Abf = (short*)(base + oKb);         // alias: dead before kb written
        short* wvb = (short*)(base + oBbf);        // alias: Bbf dead after kv-gemm
        short* Yf  = (short*)(base + oQb);         // alias: qb dead after attention
        float* stQ = (float*)(base + oSt);
        float* stK = stQ + 1024;
        float* stV = stQ + 2048;
        float* stF = stQ + 3072;

        hipMemsetAsync(stQ, 0, 16384, stream);

        // bf16 conversions (K padded to 288 / 576)
        cvt_pad<<<32768, 256, 0, stream>>>(A, Abf, 256, 288);
        cvt_pad<<<131072, 256, 0, stream>>>(B, Bbf, 265, 288);
        cvt_pad<<<512, 256, 0, stream>>>(Wq, Wqb, 256, 288);
        cvt_pad<<<512, 256, 0, stream>>>(Wk, Wkb, 265, 288);
        cvt_pad<<<512, 256, 0, stream>>>(Wv, Wvb, 265, 288);
        cvt_pad<<<256, 256, 0, stream>>>(Wf, Wfb, 512, 576);

        // q projection: 128 m-tiles (256 rows) x 4 n-blocks, swizzled
        gemm256<<<512, 256, 0, stream>>>(
            Abf, Wqb, Wqb, bq, bq, qb, qb, stQ, stQ, 512, 288, a_lens, 7, 2, 0);
        // fused k+v: 512 m-tiles x 4 n x {v,k}, swizzled (clobbers Abf)
        gemm256<<<4096, 256, 0, stream>>>(
            Bbf, Wvb, Wkb, bv, bk, Yv, kb, stV, stK, 512, 288, b_lens, 9, 3, 1);

        finalize_stats<<<1, 512, 0, stream>>>(stV, gv, betav, b_lens, 512);
        finalize_stats<<<1, 512, 0, stream>>>(stK, gk, betak, b_lens, 512);
        finalize_stats<<<1, 512, 0, stream>>>(stQ, gq, betaq, a_lens, 512);
        apply_norm512<<<32768, 256, 0, stream>>>(Yv, stV);
        apply_norm512<<<32768, 256, 0, stream>>>(kb, stK);
        apply_norm512<<<8192, 256, 0, stream>>>(qb, stQ);

        // attention (v row-major; writes wv incl. zeroed pad cols)
        attention<<<512, 256, 0, stream>>>(qb, kb, Yv, b_lens, wvb, 576);

        // f projection: 128 m-tiles x 2 n-blocks, swizzled (K=576)
        gemm256<<<256, 256, 0, stream>>>(
            wvb, Wfb, Wfb, bfp, bfp, Yf, Yf, stF, stF, 256, 576, a_lens, 7, 1, 0);
        finalize_stats<<<1, 512, 0, stream>>>(stF, gf, betaf, a_lens, 256);
        apply_f<<<8192, 256, 0, stream>>>(Yf, stF, a_lens, out);
        return;
    }

    // ---- fallback: R1-style path (peak ~335.6 MB, known correct) ----
    short* qb  = (short*)(base);
    short* Yv  = (short*)(base + 33554432);
    short* kb  = (short*)(base + 33554432 + 134217728);
    short* wvb = (short*)(base + 33554432 + 2L * 134217728);
    float* stQ = (float*)(base + 2L * 33554432 + 2L * 134217728);
    float* stK = stQ + 1024;
    float* stV = stQ + 2048;
    float* stF = stQ + 3072;
    short* Yf  = qb;

    hipMemsetAsync(stQ, 0, 16384, stream);

    gemm_bt<false, true><<<dim3(256, 4), 256, 0, stream>>>(
        A, Wq, bq, qb, 512, 256, 256, stQ, a_lens, 7);
    gemm_bt<false, false><<<dim3(1024, 4), 256, 0, stream>>>(
        B, Wv, bv, Yv, 512, 265, 288, stV, b_lens, 9);
    finalize_stats<<<1, 512, 0, stream>>>(stV, gv, betav, b_lens, 512);
    apply_norm512<<<32768, 256, 0, stream>>>(Yv, stV);
    gemm_bt<false, false><<<dim3(1024, 4), 256, 0, stream>>>(
        B, Wk, bk, kb, 512, 265, 288, stK, b_lens, 9);
    finalize_stats<<<1, 512, 0, stream>>>(stK, gk, betak, b_lens, 512);
    apply_norm512<<<32768, 256, 0, stream>>>(kb, stK);
    finalize_stats<<<1, 512, 0, stream>>>(stQ, gq, betaq, a_lens, 512);
    apply_norm512<<<8192, 256, 0, stream>>>(qb, stQ);
    attention<<<512, 256, 0, stream>>>(qb, kb, Yv, b_lens, wvb, 512);
    gemm_bt<true, true><<<dim3(256, 2), 256, 0, stream>>>(
        wvb, Wf, bfp, Yf, 256, 512, 512, stF, a_lens, 7);
    finalize_stats<<<1, 512, 0, stream>>>(stF, gf, betaf, a_lens, 256);
    apply_f<<<8192, 256, 0, stream>>>(Yf, stF, a_lens, out);
}